// Round 7
// baseline (299.352 us; speedup 1.0000x reference)
//
#include <hip/hip_runtime.h>

#define N_NODES   50000
#define N_EDGES   800000
#define DIM       128
#define N_GRAPHS  64
#define N_CLASSES 10
#define NCHUNK    16
#define NPB       128      // nodes per block in k_node
#define PASSN     32       // nodes staged per pass in k_node
#define NCHUNK_E  32       // edge chunks for LDS histogram
#define CHUNK_SZ  (N_EDGES / NCHUNK_E)     // 25000
#define LHALF     (N_NODES / 2)            // 25000 packed words (2 nodes/word)
#define NB2       ((LHALF + 255) / 256)    // 98 reduce/scan blocks (512 nodes each)

// ---- per-chunk LDS histograms of dst and src (16-bit packed, 2 nodes/word) --
// Zero global atomics: counts land in LDS, dumped as sequential writes.
__global__ __launch_bounds__(512) void k_lhist(const int* __restrict__ src,
                                               const int* __restrict__ dst,
                                               unsigned* __restrict__ Hin,
                                               unsigned* __restrict__ Hout) {
    __shared__ unsigned L[LHALF];          // 100 KB
    int c = blockIdx.x, t = threadIdx.x;
    int base = c * CHUNK_SZ;
    // phase 1: dst histogram
    for (int w = t; w < LHALF; w += 512) L[w] = 0u;
    __syncthreads();
    for (int i = t; i < CHUNK_SZ; i += 512) {
        int d = dst[base + i];
        atomicAdd(&L[d >> 1], (d & 1) ? 0x10000u : 1u);
    }
    __syncthreads();
    for (int w = t; w < LHALF; w += 512) Hin[(size_t)c * LHALF + w] = L[w];
    __syncthreads();
    // phase 2: src histogram
    for (int w = t; w < LHALF; w += 512) L[w] = 0u;
    __syncthreads();
    for (int i = t; i < CHUNK_SZ; i += 512) {
        int s = src[base + i];
        atomicAdd(&L[s >> 1], (s & 1) ? 0x10000u : 1u);
    }
    __syncthreads();
    for (int w = t; w < LHALF; w += 512) Hout[(size_t)c * LHALF + w] = L[w];
}

// ---- reduce chunks -> degrees/norms; Hin := per-chunk exclusive prefix; -----
// graph boundaries (gid sorted); fused block-level scan of indeg (512 nodes/blk)
__global__ __launch_bounds__(256) void k_reduce(unsigned* __restrict__ Hin,
                                                const unsigned* __restrict__ Hout,
                                                const int* __restrict__ gid,
                                                unsigned* __restrict__ indeg,
                                                float* __restrict__ outnorm,
                                                float* __restrict__ innorm,
                                                int* __restrict__ start,
                                                unsigned* __restrict__ row_ptr,
                                                unsigned* __restrict__ blockSums) {
    __shared__ unsigned sB[256];
    int t = threadIdx.x;
    int w = blockIdx.x * 256 + t;          // packed word index = node pair
    unsigned r0 = 0, r1 = 0;
    if (w < LHALF) {
        // in-degree: per-chunk exclusive prefix written back (packed u16;
        // safe: total indeg per node << 65536 for this graph)
        for (int c = 0; c < NCHUNK_E; ++c) {
            size_t idx = (size_t)c * LHALF + w;
            unsigned word = Hin[idx];
            Hin[idx] = r0 | (r1 << 16);
            r0 += word & 0xffffu;
            r1 += word >> 16;
        }
        unsigned o0 = 0, o1 = 0;
        for (int c = 0; c < NCHUNK_E; ++c) {
            unsigned word = Hout[(size_t)c * LHALF + w];
            o0 += word & 0xffffu;
            o1 += word >> 16;
        }
        int n0 = 2 * w, n1 = 2 * w + 1;
        indeg[n0] = r0;               indeg[n1] = r1;
        innorm[n0] = rsqrtf(fmaxf((float)r0, 1.0f));
        innorm[n1] = rsqrtf(fmaxf((float)r1, 1.0f));
        outnorm[n0] = rsqrtf(fmaxf((float)o0, 1.0f));
        outnorm[n1] = rsqrtf(fmaxf((float)o1, 1.0f));
        // graph boundary detection (graph_ids sorted)
#pragma unroll
        for (int j = 0; j < 2; ++j) {
            int i = 2 * w + j;
            int g = gid[i];
            if (i == 0) {
                for (int x = 0; x <= g; ++x) start[x] = 0;
            } else {
                int gp = gid[i - 1];
                if (gp != g)
                    for (int x = gp + 1; x <= g; ++x) start[x] = i;
            }
            if (i == N_NODES - 1)
                for (int x = g + 1; x <= N_GRAPHS; ++x) start[x] = N_NODES;
        }
    }
    // fused scan pass 1 over this block's 512 nodes (pairs)
    unsigned pair = (w < LHALF) ? (r0 + r1) : 0u;
    sB[t] = pair;
    __syncthreads();
    for (int off = 1; off < 256; off <<= 1) {
        unsigned x = (t >= off) ? sB[t - off] : 0u;
        __syncthreads();
        sB[t] += x;
        __syncthreads();
    }
    if (w < LHALF) {
        unsigned excl = sB[t] - pair;
        row_ptr[2 * w]     = excl;
        row_ptr[2 * w + 1] = excl + r0;
    }
    if (t == 255) blockSums[blockIdx.x] = sB[255];
}

// ---- scan pass 2 over NB2 block sums ----------------------------------------
__global__ __launch_bounds__(256) void k_scan2(unsigned* __restrict__ blockSums,
                                               unsigned* __restrict__ blockOff) {
    __shared__ unsigned s[256];
    int t = threadIdx.x;
    unsigned val = (t < NB2) ? blockSums[t] : 0u;
    s[t] = val;
    __syncthreads();
    for (int off = 1; off < 256; off <<= 1) {
        unsigned x = (t >= off) ? s[t - off] : 0u;
        __syncthreads();
        s[t] += x;
        __syncthreads();
    }
    if (t < NB2) blockOff[t] = s[t] - val;
}

// ---- scatter edges into CSR buckets — LDS ranks, zero global atomics --------
__global__ __launch_bounds__(512) void k_scatter2(const int* __restrict__ src,
                                                  const int* __restrict__ dst,
                                                  const unsigned* __restrict__ Hin,
                                                  const unsigned* __restrict__ row_ptr,
                                                  const unsigned* __restrict__ blockOff,
                                                  int* __restrict__ bsrc) {
    __shared__ unsigned L[LHALF];          // 100 KB rank counters
    int c = blockIdx.x, t = threadIdx.x;
    int base = c * CHUNK_SZ;
    for (int w = t; w < LHALF; w += 512) L[w] = 0u;
    __syncthreads();
    for (int i = t; i < CHUNK_SZ; i += 512) {
        int d = dst[base + i];
        int sh = (d & 1) * 16;
        unsigned old = atomicAdd(&L[d >> 1], (d & 1) ? 0x10000u : 1u);
        unsigned rank = (old >> sh) & 0xffffu;
        unsigned pre  = (Hin[(size_t)c * LHALF + (d >> 1)] >> sh) & 0xffffu;
        unsigned pos = row_ptr[d] + blockOff[d >> 9] + pre + rank;
        bsrc[pos] = src[base + i];
    }
}

// ---- gather-sum: agg[n] = innorm[n] * sum_{e: dst=n} feat[src_e]*outnorm[src_e]
__global__ __launch_bounds__(256) void k_gather(const int* __restrict__ bsrc,
                                                const unsigned* __restrict__ row_ptr,
                                                const unsigned* __restrict__ blockOff,
                                                const unsigned* __restrict__ indeg,
                                                const float* __restrict__ feat,
                                                const float* __restrict__ outnorm,
                                                const float* __restrict__ innorm,
                                                float* __restrict__ agg) {
    int tid = threadIdx.x;
    int wave = tid >> 6;
    int lane = tid & 63;
    int node = blockIdx.x * 4 + wave;
    if (node >= N_NODES) return;
    unsigned start = row_ptr[node] + blockOff[node >> 9];
    unsigned deg   = indeg[node];
    int half = lane >> 5;
    int q    = (lane & 31) << 2;
    float4 acc  = {0.f, 0.f, 0.f, 0.f};
    float4 acc2 = {0.f, 0.f, 0.f, 0.f};
    unsigned j = 0;
    for (; j + 4 <= deg; j += 4) {
        int s0 = bsrc[start + j + half];
        int s1 = bsrc[start + j + 2 + half];
        float n0 = outnorm[s0];
        float n1 = outnorm[s1];
        float4 v0 = *reinterpret_cast<const float4*>(feat + (size_t)s0 * DIM + q);
        float4 v1 = *reinterpret_cast<const float4*>(feat + (size_t)s1 * DIM + q);
        acc.x  += v0.x * n0; acc.y  += v0.y * n0; acc.z  += v0.z * n0; acc.w  += v0.w * n0;
        acc2.x += v1.x * n1; acc2.y += v1.y * n1; acc2.z += v1.z * n1; acc2.w += v1.w * n1;
    }
    for (; j < deg; j += 2) {
        unsigned jj = j + half;
        bool valid = (jj < deg);
        int s = bsrc[start + (valid ? jj : 0u)];
        float nrm = valid ? outnorm[s] : 0.0f;
        float4 v = *reinterpret_cast<const float4*>(feat + (size_t)s * DIM + q);
        acc.x += v.x * nrm; acc.y += v.y * nrm; acc.z += v.z * nrm; acc.w += v.w * nrm;
    }
    acc.x += acc2.x; acc.y += acc2.y; acc.z += acc2.z; acc.w += acc2.w;
    acc.x += __shfl_down(acc.x, 32);
    acc.y += __shfl_down(acc.y, 32);
    acc.z += __shfl_down(acc.z, 32);
    acc.w += __shfl_down(acc.w, 32);
    if (half == 0) {
        float innrm = innorm[node];
        float4 r = {acc.x * innrm, acc.y * innrm, acc.z * innrm, acc.w * innrm};
        *reinterpret_cast<float4*>(agg + (size_t)node * DIM + q) = r;
    }
}

#define FMA4(ACC, S, WV) ACC.x += (S) * WV.x; ACC.y += (S) * WV.y; \
                         ACC.z += (S) * WV.z; ACC.w += (S) * WV.w;

// ---- node transform: h = relu(agg @ W + b), in place. 4 nodes x 4 outs/thread
__global__ __launch_bounds__(256) void k_node(float* __restrict__ agg,
                                              const float* __restrict__ W,
                                              const float* __restrict__ b) {
    __shared__ float sW[DIM * DIM];        // 64 KB
    __shared__ float srow[PASSN][DIM];     // 16 KB
    int tid = threadIdx.x;
    for (int i = tid; i < DIM * DIM; i += 256) sW[i] = W[i];

    int o  = (tid & 31) << 2;
    int n0 = (tid >> 5) << 2;
    float4 bb = *reinterpret_cast<const float4*>(b + o);

    int blockBase = blockIdx.x * NPB;
    for (int p = 0; p < NPB / PASSN; ++p) {
        int base = blockBase + p * PASSN;
        __syncthreads();
        for (int i = tid; i < PASSN * 32; i += 256) {
            int n = i >> 5, d4 = (i & 31) << 2;
            int node = base + n;
            float4 v = {0.f, 0.f, 0.f, 0.f};
            if (node < N_NODES)
                v = *reinterpret_cast<const float4*>(agg + (size_t)node * DIM + d4);
            *reinterpret_cast<float4*>(&srow[n][d4]) = v;
        }
        __syncthreads();
        float4 acc0 = {0,0,0,0}, acc1 = {0,0,0,0}, acc2 = {0,0,0,0}, acc3 = {0,0,0,0};
#pragma unroll 4
        for (int k = 0; k < DIM; k += 4) {
            float4 w0 = *reinterpret_cast<const float4*>(&sW[(k + 0) * DIM + o]);
            float4 w1 = *reinterpret_cast<const float4*>(&sW[(k + 1) * DIM + o]);
            float4 w2 = *reinterpret_cast<const float4*>(&sW[(k + 2) * DIM + o]);
            float4 w3 = *reinterpret_cast<const float4*>(&sW[(k + 3) * DIM + o]);
            float4 a0 = *reinterpret_cast<const float4*>(&srow[n0 + 0][k]);
            float4 a1 = *reinterpret_cast<const float4*>(&srow[n0 + 1][k]);
            float4 a2 = *reinterpret_cast<const float4*>(&srow[n0 + 2][k]);
            float4 a3 = *reinterpret_cast<const float4*>(&srow[n0 + 3][k]);
            FMA4(acc0, a0.x, w0); FMA4(acc0, a0.y, w1); FMA4(acc0, a0.z, w2); FMA4(acc0, a0.w, w3);
            FMA4(acc1, a1.x, w0); FMA4(acc1, a1.y, w1); FMA4(acc1, a1.z, w2); FMA4(acc1, a1.w, w3);
            FMA4(acc2, a2.x, w0); FMA4(acc2, a2.y, w1); FMA4(acc2, a2.z, w2); FMA4(acc2, a2.w, w3);
            FMA4(acc3, a3.x, w0); FMA4(acc3, a3.y, w1); FMA4(acc3, a3.z, w2); FMA4(acc3, a3.w, w3);
        }
        __syncthreads();
        float4 accs[4] = {acc0, acc1, acc2, acc3};
#pragma unroll
        for (int j = 0; j < 4; ++j) {
            int node = base + n0 + j;
            if (node < N_NODES) {
                float4 h;
                h.x = fmaxf(accs[j].x + bb.x, 0.0f);
                h.y = fmaxf(accs[j].y + bb.y, 0.0f);
                h.z = fmaxf(accs[j].z + bb.z, 0.0f);
                h.w = fmaxf(accs[j].w + bb.w, 0.0f);
                *reinterpret_cast<float4*>(agg + (size_t)node * DIM + o) = h;
            }
        }
    }
}

// ---- graph sum-pool, parallel: grid (G, NCHUNK); atomics into zeroed pooled -
__global__ __launch_bounds__(256) void k_pool(const float* __restrict__ h,
                                              const int* __restrict__ start,
                                              float* __restrict__ pooled) {
    __shared__ float red[8][DIM];
    int g = blockIdx.x;
    int chunk = blockIdx.y;
    int t = threadIdx.x;
    int slot = t >> 5;
    int q    = (t & 31) << 2;
    int s = start[g], e = start[g + 1];
    float4 acc = {0.f, 0.f, 0.f, 0.f};
    for (int n = s + chunk * 8 + slot; n < e; n += NCHUNK * 8) {
        float4 v = *reinterpret_cast<const float4*>(h + (size_t)n * DIM + q);
        acc.x += v.x; acc.y += v.y; acc.z += v.z; acc.w += v.w;
    }
    *reinterpret_cast<float4*>(&red[slot][q]) = acc;
    __syncthreads();
    if (t < DIM) {
        float sum = 0.f;
#pragma unroll
        for (int r = 0; r < 8; ++r) sum += red[r][t];
        atomicAdd(&pooled[g * DIM + t], sum);
    }
}

// ---- head: out = (pooled/cnt) @ W_head + b_head -----------------------------
__global__ __launch_bounds__(256) void k_head(const float* __restrict__ pooled,
                                              const int* __restrict__ start,
                                              const float* __restrict__ Wh,
                                              const float* __restrict__ bh,
                                              float* __restrict__ out) {
    int i = blockIdx.x * 256 + threadIdx.x;
    if (i >= N_GRAPHS * N_CLASSES) return;
    int g = i / N_CLASSES, c = i % N_CLASSES;
    const float* pr = pooled + g * DIM;
    float s = 0.f;
#pragma unroll 8
    for (int k = 0; k < DIM; ++k) s += pr[k] * Wh[k * N_CLASSES + c];
    float cntf = fmaxf((float)(start[g + 1] - start[g]), 1.0f);
    out[i] = s / cntf + bh[c];
}

extern "C" void kernel_launch(void* const* d_in, const int* in_sizes, int n_in,
                              void* d_out, int out_size, void* d_ws, size_t ws_size,
                              hipStream_t stream) {
    const float* feat = (const float*)d_in[0];
    const int*   src  = (const int*)d_in[1];
    const int*   dst  = (const int*)d_in[2];
    const int*   gid  = (const int*)d_in[3];
    const float* W    = (const float*)d_in[4];
    const float* b    = (const float*)d_in[5];
    const float* Wh   = (const float*)d_in[6];
    const float* bh   = (const float*)d_in[7];
    float* out = (float*)d_out;

    // ---- workspace layout (4-byte elements) ----
    float*    pooled   = (float*)d_ws;                                  // G*D (zeroed)
    unsigned* indeg    = (unsigned*)(pooled + (size_t)N_GRAPHS * DIM);  // N
    float*    outnorm  = (float*)(indeg + N_NODES);                     // N
    float*    innorm   = outnorm + N_NODES;                             // N
    int*      start    = (int*)(innorm + N_NODES);                      // G+1
    unsigned* row_ptr  = (unsigned*)(start + N_GRAPHS + 1);             // N
    unsigned* blockSums= row_ptr + N_NODES;                             // 256
    unsigned* blockOff = blockSums + 256;                               // 256
    int*      bsrc     = (int*)(blockOff + 256);                        // E
    float*    agg      = (float*)(bsrc + N_EDGES);                      // N*D (reused as h)
    // Hin/Hout alias agg: consumed by k_reduce/k_scatter2 before k_gather writes agg
    unsigned* Hin      = (unsigned*)agg;                                // 32*LHALF
    unsigned* Hout     = Hin + (size_t)NCHUNK_E * LHALF;                // 32*LHALF

    hipMemsetAsync(pooled, 0, (size_t)N_GRAPHS * DIM * 4, stream);

    k_lhist   <<<NCHUNK_E, 512, 0, stream>>>(src, dst, Hin, Hout);
    k_reduce  <<<NB2, 256, 0, stream>>>(Hin, Hout, gid, indeg, outnorm, innorm,
                                        start, row_ptr, blockSums);
    k_scan2   <<<1, 256, 0, stream>>>(blockSums, blockOff);
    k_scatter2<<<NCHUNK_E, 512, 0, stream>>>(src, dst, Hin, row_ptr, blockOff, bsrc);
    k_gather  <<<(N_NODES + 3) / 4, 256, 0, stream>>>(bsrc, row_ptr, blockOff, indeg,
                                                      feat, outnorm, innorm, agg);
    k_node    <<<(N_NODES + NPB - 1) / NPB, 256, 0, stream>>>(agg, W, b);
    dim3 pg(N_GRAPHS, NCHUNK);
    k_pool    <<<pg, 256, 0, stream>>>(agg, start, pooled);
    k_head    <<<3, 256, 0, stream>>>(pooled, start, Wh, bh, out);
}

// Round 8
// 261.350 us; speedup vs baseline: 1.1454x; 1.1454x over previous
//
#include <hip/hip_runtime.h>

#define N_NODES   50000
#define N_EDGES   800000
#define DIM       128
#define N_GRAPHS  64
#define N_CLASSES 10
#define NCHUNK    16
#define NPB       128                  // nodes per block in k_node
#define PASSN     32                   // nodes staged per pass in k_node
#define NCHE      256                  // edge chunks (one block each, all CUs busy)
#define CSZ       (N_EDGES / NCHE)     // 3125
#define LQ        (N_NODES / 4)        // 12500 u8-packed words (4 nodes/word)
#define NBR       ((LQ + 255) / 256)   // 49 reduce blocks (1024 nodes each)

// ---- per-chunk LDS histograms (u8 packed, 4 nodes/word), rank captured ------
// Zero global atomics. Safe: max total degree ~45 << 255.
__global__ __launch_bounds__(256) void k_lhist(const int* __restrict__ src,
                                               const int* __restrict__ dst,
                                               unsigned* __restrict__ Hin,
                                               unsigned* __restrict__ Hout,
                                               unsigned char* __restrict__ perm) {
    __shared__ unsigned L[LQ];         // 50 KB
    int c = blockIdx.x, t = threadIdx.x;
    int base = c * CSZ;
    for (int w = t; w < LQ; w += 256) L[w] = 0u;
    __syncthreads();
    for (int i = t; i < CSZ; i += 256) {
        int d = dst[base + i];
        int sh = (d & 3) * 8;
        unsigned old = atomicAdd(&L[d >> 2], 1u << sh);
        perm[base + i] = (unsigned char)((old >> sh) & 0xffu);
    }
    __syncthreads();
    for (int w = t; w < LQ; w += 256) Hin[(size_t)c * LQ + w] = L[w];
    __syncthreads();
    for (int w = t; w < LQ; w += 256) L[w] = 0u;
    __syncthreads();
    for (int i = t; i < CSZ; i += 256) {
        int s = src[base + i];
        atomicAdd(&L[s >> 2], 1u << ((s & 3) * 8));
    }
    __syncthreads();
    for (int w = t; w < LQ; w += 256) Hout[(size_t)c * LQ + w] = L[w];
}

// ---- reduce chunks: degrees/norms; Hin := per-chunk exclusive prefix (u8); --
// graph boundaries (gid sorted); fused scan pass 1 (1024 nodes/block)
__global__ __launch_bounds__(256) void k_reduce(unsigned* __restrict__ Hin,
                                                const unsigned* __restrict__ Hout,
                                                const int* __restrict__ gid,
                                                unsigned* __restrict__ indeg,
                                                float* __restrict__ outnorm,
                                                float* __restrict__ innorm,
                                                int* __restrict__ start,
                                                unsigned* __restrict__ row_ptr,
                                                unsigned* __restrict__ blockSums) {
    __shared__ unsigned sB[256];
    int t = threadIdx.x;
    int w = blockIdx.x * 256 + t;      // u8-packed word = 4 nodes
    unsigned r0 = 0, r1 = 0, r2 = 0, r3 = 0;
    if (w < LQ) {
        for (int c = 0; c < NCHE; ++c) {
            size_t idx = (size_t)c * LQ + w;
            unsigned word = Hin[idx];
            Hin[idx] = r0 | (r1 << 8) | (r2 << 16) | (r3 << 24);
            r0 += word & 0xffu;
            r1 += (word >> 8) & 0xffu;
            r2 += (word >> 16) & 0xffu;
            r3 += word >> 24;
        }
        unsigned o0 = 0, o1 = 0, o2 = 0, o3 = 0;
        for (int c = 0; c < NCHE; ++c) {
            unsigned word = Hout[(size_t)c * LQ + w];
            o0 += word & 0xffu;
            o1 += (word >> 8) & 0xffu;
            o2 += (word >> 16) & 0xffu;
            o3 += word >> 24;
        }
        int n = 4 * w;
        unsigned rr[4] = {r0, r1, r2, r3};
        unsigned oo[4] = {o0, o1, o2, o3};
#pragma unroll
        for (int j = 0; j < 4; ++j) {
            indeg[n + j]   = rr[j];
            innorm[n + j]  = rsqrtf(fmaxf((float)rr[j], 1.0f));
            outnorm[n + j] = rsqrtf(fmaxf((float)oo[j], 1.0f));
            int i = n + j;
            int g = gid[i];
            if (i == 0) {
                for (int x = 0; x <= g; ++x) start[x] = 0;
            } else {
                int gp = gid[i - 1];
                if (gp != g)
                    for (int x = gp + 1; x <= g; ++x) start[x] = i;
            }
            if (i == N_NODES - 1)
                for (int x = g + 1; x <= N_GRAPHS; ++x) start[x] = N_NODES;
        }
    }
    unsigned tot = r0 + r1 + r2 + r3;
    sB[t] = tot;
    __syncthreads();
    for (int off = 1; off < 256; off <<= 1) {
        unsigned x = (t >= off) ? sB[t - off] : 0u;
        __syncthreads();
        sB[t] += x;
        __syncthreads();
    }
    if (w < LQ) {
        unsigned ex = sB[t] - tot;
        row_ptr[4 * w]     = ex;
        row_ptr[4 * w + 1] = ex + r0;
        row_ptr[4 * w + 2] = ex + r0 + r1;
        row_ptr[4 * w + 3] = ex + r0 + r1 + r2;
    }
    if (t == 255) blockSums[blockIdx.x] = sB[255];
}

// ---- scan pass 2 over NBR block sums ----------------------------------------
__global__ __launch_bounds__(256) void k_scan2(unsigned* __restrict__ blockSums,
                                               unsigned* __restrict__ blockOff) {
    __shared__ unsigned s[256];
    int t = threadIdx.x;
    unsigned val = (t < NBR) ? blockSums[t] : 0u;
    s[t] = val;
    __syncthreads();
    for (int off = 1; off < 256; off <<= 1) {
        unsigned x = (t >= off) ? s[t - off] : 0u;
        __syncthreads();
        s[t] += x;
        __syncthreads();
    }
    if (t < NBR) blockOff[t] = s[t] - val;
}

// ---- place edges into CSR buckets — pure streaming, zero atomics ------------
__global__ __launch_bounds__(256) void k_place(const int* __restrict__ src,
                                               const int* __restrict__ dst,
                                               const unsigned* __restrict__ Hin,
                                               const unsigned char* __restrict__ perm,
                                               const unsigned* __restrict__ row_ptr,
                                               const unsigned* __restrict__ blockOff,
                                               int* __restrict__ bsrc) {
    int c = blockIdx.y;
    int i = blockIdx.x * 256 + threadIdx.x;
    if (i >= CSZ) return;
    int e = c * CSZ + i;
    int d = dst[e];
    int sh = (d & 3) * 8;
    unsigned pre = (Hin[(size_t)c * LQ + (d >> 2)] >> sh) & 0xffu;
    unsigned pos = row_ptr[d] + blockOff[d >> 10] + pre + perm[e];
    bsrc[pos] = src[e];
}

// ---- gather-sum with shfl-staged indices (kills the dependent-load chain) ---
__global__ __launch_bounds__(256) void k_gather(const int* __restrict__ bsrc,
                                                const unsigned* __restrict__ row_ptr,
                                                const unsigned* __restrict__ blockOff,
                                                const unsigned* __restrict__ indeg,
                                                const float* __restrict__ feat,
                                                const float* __restrict__ outnorm,
                                                const float* __restrict__ innorm,
                                                float* __restrict__ agg) {
    int tid = threadIdx.x;
    int wave = tid >> 6;
    int lane = tid & 63;
    int node = blockIdx.x * 4 + wave;
    if (node >= N_NODES) return;
    unsigned start = row_ptr[node] + blockOff[node >> 10];
    unsigned deg   = indeg[node];
    unsigned lim   = deg < 64u ? deg : 64u;
    int half = lane >> 5;
    int q    = (lane & 31) << 2;
    // stage up to 64 edge indices + norms (one coalesced load + one gather)
    int   sIdx = 0;
    float sNrm = 0.f;
    if ((unsigned)lane < lim) {
        sIdx = bsrc[start + lane];
        sNrm = outnorm[sIdx];
    }
    float4 acc  = {0.f, 0.f, 0.f, 0.f};
    float4 acc2 = {0.f, 0.f, 0.f, 0.f};
    unsigned j = 0;
    for (; j + 4 <= lim; j += 4) {
        int   s0 = __shfl(sIdx, (int)(j + half));
        float n0 = __shfl(sNrm, (int)(j + half));
        int   s1 = __shfl(sIdx, (int)(j + 2 + half));
        float n1 = __shfl(sNrm, (int)(j + 2 + half));
        float4 v0 = *reinterpret_cast<const float4*>(feat + (size_t)s0 * DIM + q);
        float4 v1 = *reinterpret_cast<const float4*>(feat + (size_t)s1 * DIM + q);
        acc.x  += v0.x * n0; acc.y  += v0.y * n0; acc.z  += v0.z * n0; acc.w  += v0.w * n0;
        acc2.x += v1.x * n1; acc2.y += v1.y * n1; acc2.z += v1.z * n1; acc2.w += v1.w * n1;
    }
    for (; j < lim; j += 2) {
        unsigned jj = j + half;
        unsigned sl = jj < 63u ? jj : 63u;
        int   s  = __shfl(sIdx, (int)sl);
        float nm = __shfl(sNrm, (int)sl);
        if (jj >= lim) nm = 0.f;
        float4 v = *reinterpret_cast<const float4*>(feat + (size_t)s * DIM + q);
        acc.x += v.x * nm; acc.y += v.y * nm; acc.z += v.z * nm; acc.w += v.w * nm;
    }
    // overflow (deg > 64): direct loads — statistically never for this graph
    for (j = 64; j < deg; j += 2) {
        unsigned jj = j + half;
        bool valid = (jj < deg);
        int s = bsrc[start + (valid ? jj : 0u)];
        float nm = valid ? outnorm[s] : 0.f;
        float4 v = *reinterpret_cast<const float4*>(feat + (size_t)s * DIM + q);
        acc2.x += v.x * nm; acc2.y += v.y * nm; acc2.z += v.z * nm; acc2.w += v.w * nm;
    }
    acc.x += acc2.x; acc.y += acc2.y; acc.z += acc2.z; acc.w += acc2.w;
    acc.x += __shfl_down(acc.x, 32);
    acc.y += __shfl_down(acc.y, 32);
    acc.z += __shfl_down(acc.z, 32);
    acc.w += __shfl_down(acc.w, 32);
    if (half == 0) {
        float innrm = innorm[node];
        float4 r = {acc.x * innrm, acc.y * innrm, acc.z * innrm, acc.w * innrm};
        *reinterpret_cast<float4*>(agg + (size_t)node * DIM + q) = r;
    }
}

#define FMA4(ACC, S, WV) ACC.x += (S) * WV.x; ACC.y += (S) * WV.y; \
                         ACC.z += (S) * WV.z; ACC.w += (S) * WV.w;

// ---- node transform: h = relu(agg @ W + b), in place. 4 nodes x 4 outs/thread
__global__ __launch_bounds__(256) void k_node(float* __restrict__ agg,
                                              const float* __restrict__ W,
                                              const float* __restrict__ b) {
    __shared__ float sW[DIM * DIM];        // 64 KB
    __shared__ float srow[PASSN][DIM];     // 16 KB
    int tid = threadIdx.x;
    for (int i = tid; i < DIM * DIM; i += 256) sW[i] = W[i];

    int o  = (tid & 31) << 2;
    int n0 = (tid >> 5) << 2;
    float4 bb = *reinterpret_cast<const float4*>(b + o);

    int blockBase = blockIdx.x * NPB;
    for (int p = 0; p < NPB / PASSN; ++p) {
        int base = blockBase + p * PASSN;
        __syncthreads();
        for (int i = tid; i < PASSN * 32; i += 256) {
            int n = i >> 5, d4 = (i & 31) << 2;
            int node = base + n;
            float4 v = {0.f, 0.f, 0.f, 0.f};
            if (node < N_NODES)
                v = *reinterpret_cast<const float4*>(agg + (size_t)node * DIM + d4);
            *reinterpret_cast<float4*>(&srow[n][d4]) = v;
        }
        __syncthreads();
        float4 acc0 = {0,0,0,0}, acc1 = {0,0,0,0}, acc2 = {0,0,0,0}, acc3 = {0,0,0,0};
#pragma unroll 4
        for (int k = 0; k < DIM; k += 4) {
            float4 w0 = *reinterpret_cast<const float4*>(&sW[(k + 0) * DIM + o]);
            float4 w1 = *reinterpret_cast<const float4*>(&sW[(k + 1) * DIM + o]);
            float4 w2 = *reinterpret_cast<const float4*>(&sW[(k + 2) * DIM + o]);
            float4 w3 = *reinterpret_cast<const float4*>(&sW[(k + 3) * DIM + o]);
            float4 a0 = *reinterpret_cast<const float4*>(&srow[n0 + 0][k]);
            float4 a1 = *reinterpret_cast<const float4*>(&srow[n0 + 1][k]);
            float4 a2 = *reinterpret_cast<const float4*>(&srow[n0 + 2][k]);
            float4 a3 = *reinterpret_cast<const float4*>(&srow[n0 + 3][k]);
            FMA4(acc0, a0.x, w0); FMA4(acc0, a0.y, w1); FMA4(acc0, a0.z, w2); FMA4(acc0, a0.w, w3);
            FMA4(acc1, a1.x, w0); FMA4(acc1, a1.y, w1); FMA4(acc1, a1.z, w2); FMA4(acc1, a1.w, w3);
            FMA4(acc2, a2.x, w0); FMA4(acc2, a2.y, w1); FMA4(acc2, a2.z, w2); FMA4(acc2, a2.w, w3);
            FMA4(acc3, a3.x, w0); FMA4(acc3, a3.y, w1); FMA4(acc3, a3.z, w2); FMA4(acc3, a3.w, w3);
        }
        __syncthreads();
        float4 accs[4] = {acc0, acc1, acc2, acc3};
#pragma unroll
        for (int j = 0; j < 4; ++j) {
            int node = base + n0 + j;
            if (node < N_NODES) {
                float4 h;
                h.x = fmaxf(accs[j].x + bb.x, 0.0f);
                h.y = fmaxf(accs[j].y + bb.y, 0.0f);
                h.z = fmaxf(accs[j].z + bb.z, 0.0f);
                h.w = fmaxf(accs[j].w + bb.w, 0.0f);
                *reinterpret_cast<float4*>(agg + (size_t)node * DIM + o) = h;
            }
        }
    }
}

// ---- graph sum-pool, parallel: grid (G, NCHUNK); atomics into zeroed pooled -
__global__ __launch_bounds__(256) void k_pool(const float* __restrict__ h,
                                              const int* __restrict__ start,
                                              float* __restrict__ pooled) {
    __shared__ float red[8][DIM];
    int g = blockIdx.x;
    int chunk = blockIdx.y;
    int t = threadIdx.x;
    int slot = t >> 5;
    int q    = (t & 31) << 2;
    int s = start[g], e = start[g + 1];
    float4 acc = {0.f, 0.f, 0.f, 0.f};
    for (int n = s + chunk * 8 + slot; n < e; n += NCHUNK * 8) {
        float4 v = *reinterpret_cast<const float4*>(h + (size_t)n * DIM + q);
        acc.x += v.x; acc.y += v.y; acc.z += v.z; acc.w += v.w;
    }
    *reinterpret_cast<float4*>(&red[slot][q]) = acc;
    __syncthreads();
    if (t < DIM) {
        float sum = 0.f;
#pragma unroll
        for (int r = 0; r < 8; ++r) sum += red[r][t];
        atomicAdd(&pooled[g * DIM + t], sum);
    }
}

// ---- head: out = (pooled/cnt) @ W_head + b_head -----------------------------
__global__ __launch_bounds__(256) void k_head(const float* __restrict__ pooled,
                                              const int* __restrict__ start,
                                              const float* __restrict__ Wh,
                                              const float* __restrict__ bh,
                                              float* __restrict__ out) {
    int i = blockIdx.x * 256 + threadIdx.x;
    if (i >= N_GRAPHS * N_CLASSES) return;
    int g = i / N_CLASSES, c = i % N_CLASSES;
    const float* pr = pooled + g * DIM;
    float s = 0.f;
#pragma unroll 8
    for (int k = 0; k < DIM; ++k) s += pr[k] * Wh[k * N_CLASSES + c];
    float cntf = fmaxf((float)(start[g + 1] - start[g]), 1.0f);
    out[i] = s / cntf + bh[c];
}

extern "C" void kernel_launch(void* const* d_in, const int* in_sizes, int n_in,
                              void* d_out, int out_size, void* d_ws, size_t ws_size,
                              hipStream_t stream) {
    const float* feat = (const float*)d_in[0];
    const int*   src  = (const int*)d_in[1];
    const int*   dst  = (const int*)d_in[2];
    const int*   gid  = (const int*)d_in[3];
    const float* W    = (const float*)d_in[4];
    const float* b    = (const float*)d_in[5];
    const float* Wh   = (const float*)d_in[6];
    const float* bh   = (const float*)d_in[7];
    float* out = (float*)d_out;

    // ---- workspace layout (4-byte elements) ----
    float*    pooled   = (float*)d_ws;                                  // G*D (zeroed)
    unsigned* indeg    = (unsigned*)(pooled + (size_t)N_GRAPHS * DIM);  // N
    float*    outnorm  = (float*)(indeg + N_NODES);                     // N
    float*    innorm   = outnorm + N_NODES;                             // N
    int*      start    = (int*)(innorm + N_NODES);                      // G+1
    unsigned* row_ptr  = (unsigned*)(start + N_GRAPHS + 1);             // N
    unsigned* blockSums= row_ptr + N_NODES;                             // 256
    unsigned* blockOff = blockSums + 256;                               // 256
    unsigned char* perm= (unsigned char*)(blockOff + 256);              // E bytes
    int*      bsrc     = (int*)(perm + N_EDGES);                        // E
    float*    agg      = (float*)(bsrc + N_EDGES);                      // N*D (reused as h)
    // Hin/Hout alias agg (2*NCHE*LQ words == N*DIM exactly); consumed before k_gather
    unsigned* Hin      = (unsigned*)agg;                                // NCHE*LQ
    unsigned* Hout     = Hin + (size_t)NCHE * LQ;                       // NCHE*LQ

    hipMemsetAsync(pooled, 0, (size_t)N_GRAPHS * DIM * 4, stream);

    k_lhist  <<<NCHE, 256, 0, stream>>>(src, dst, Hin, Hout, perm);
    k_reduce <<<NBR, 256, 0, stream>>>(Hin, Hout, gid, indeg, outnorm, innorm,
                                       start, row_ptr, blockSums);
    k_scan2  <<<1, 256, 0, stream>>>(blockSums, blockOff);
    dim3 pgp((CSZ + 255) / 256, NCHE);
    k_place  <<<pgp, 256, 0, stream>>>(src, dst, Hin, perm, row_ptr, blockOff, bsrc);
    k_gather <<<(N_NODES + 3) / 4, 256, 0, stream>>>(bsrc, row_ptr, blockOff, indeg,
                                                     feat, outnorm, innorm, agg);
    k_node   <<<(N_NODES + NPB - 1) / NPB, 256, 0, stream>>>(agg, W, b);
    dim3 pg(N_GRAPHS, NCHUNK);
    k_pool   <<<pg, 256, 0, stream>>>(agg, start, pooled);
    k_head   <<<3, 256, 0, stream>>>(pooled, start, Wh, bh, out);
}

// Round 9
// 248.944 us; speedup vs baseline: 1.2025x; 1.0498x over previous
//
#include <hip/hip_runtime.h>

#define N_NODES   50000
#define N_EDGES   800000
#define DIM       128
#define N_GRAPHS  64
#define N_CLASSES 10
#define NCHUNK    16
#define NPB       128                  // nodes per block in k_node
#define PASSN     32                   // nodes staged per pass in k_node
#define NCHE      256                  // edge chunks (one block each)
#define CSZ       (N_EDGES / NCHE)     // 3125
#define LQ        (N_NODES / 4)        // 12500 u8-packed words (4 nodes/word)
#define NBR       ((LQ + 255) / 256)   // 49 reduce blocks (1024 nodes each)

typedef _Float16 h8 __attribute__((ext_vector_type(8)));

// ---- per-chunk LDS histograms (u8 packed, 4 nodes/word), rank captured ------
__global__ __launch_bounds__(256) void k_lhist(const int* __restrict__ src,
                                               const int* __restrict__ dst,
                                               unsigned* __restrict__ Hin,
                                               unsigned* __restrict__ Hout,
                                               unsigned char* __restrict__ perm) {
    __shared__ unsigned L[LQ];         // 50 KB
    int c = blockIdx.x, t = threadIdx.x;
    int base = c * CSZ;
    for (int w = t; w < LQ; w += 256) L[w] = 0u;
    __syncthreads();
    for (int i = t; i < CSZ; i += 256) {
        int d = dst[base + i];
        int sh = (d & 3) * 8;
        unsigned old = atomicAdd(&L[d >> 2], 1u << sh);
        perm[base + i] = (unsigned char)((old >> sh) & 0xffu);
    }
    __syncthreads();
    for (int w = t; w < LQ; w += 256) Hin[(size_t)c * LQ + w] = L[w];
    __syncthreads();
    for (int w = t; w < LQ; w += 256) L[w] = 0u;
    __syncthreads();
    for (int i = t; i < CSZ; i += 256) {
        int s = src[base + i];
        atomicAdd(&L[s >> 2], 1u << ((s & 3) * 8));
    }
    __syncthreads();
    for (int w = t; w < LQ; w += 256) Hout[(size_t)c * LQ + w] = L[w];
}

// ---- reduce chunks: degrees/norms; Hin := per-chunk exclusive prefix (u8); --
// graph boundaries (gid sorted); fused scan pass 1 (1024 nodes/block)
__global__ __launch_bounds__(256) void k_reduce(unsigned* __restrict__ Hin,
                                                const unsigned* __restrict__ Hout,
                                                const int* __restrict__ gid,
                                                unsigned* __restrict__ indeg,
                                                float* __restrict__ outnorm,
                                                float* __restrict__ innorm,
                                                int* __restrict__ start,
                                                unsigned* __restrict__ row_ptr,
                                                unsigned* __restrict__ blockSums) {
    __shared__ unsigned sB[256];
    int t = threadIdx.x;
    int w = blockIdx.x * 256 + t;
    unsigned r0 = 0, r1 = 0, r2 = 0, r3 = 0;
    if (w < LQ) {
        for (int c = 0; c < NCHE; ++c) {
            size_t idx = (size_t)c * LQ + w;
            unsigned word = Hin[idx];
            Hin[idx] = r0 | (r1 << 8) | (r2 << 16) | (r3 << 24);
            r0 += word & 0xffu;
            r1 += (word >> 8) & 0xffu;
            r2 += (word >> 16) & 0xffu;
            r3 += word >> 24;
        }
        unsigned o0 = 0, o1 = 0, o2 = 0, o3 = 0;
        for (int c = 0; c < NCHE; ++c) {
            unsigned word = Hout[(size_t)c * LQ + w];
            o0 += word & 0xffu;
            o1 += (word >> 8) & 0xffu;
            o2 += (word >> 16) & 0xffu;
            o3 += word >> 24;
        }
        int n = 4 * w;
        unsigned rr[4] = {r0, r1, r2, r3};
        unsigned oo[4] = {o0, o1, o2, o3};
#pragma unroll
        for (int j = 0; j < 4; ++j) {
            indeg[n + j]   = rr[j];
            innorm[n + j]  = rsqrtf(fmaxf((float)rr[j], 1.0f));
            outnorm[n + j] = rsqrtf(fmaxf((float)oo[j], 1.0f));
            int i = n + j;
            int g = gid[i];
            if (i == 0) {
                for (int x = 0; x <= g; ++x) start[x] = 0;
            } else {
                int gp = gid[i - 1];
                if (gp != g)
                    for (int x = gp + 1; x <= g; ++x) start[x] = i;
            }
            if (i == N_NODES - 1)
                for (int x = g + 1; x <= N_GRAPHS; ++x) start[x] = N_NODES;
        }
    }
    unsigned tot = r0 + r1 + r2 + r3;
    sB[t] = tot;
    __syncthreads();
    for (int off = 1; off < 256; off <<= 1) {
        unsigned x = (t >= off) ? sB[t - off] : 0u;
        __syncthreads();
        sB[t] += x;
        __syncthreads();
    }
    if (w < LQ) {
        unsigned ex = sB[t] - tot;
        row_ptr[4 * w]     = ex;
        row_ptr[4 * w + 1] = ex + r0;
        row_ptr[4 * w + 2] = ex + r0 + r1;
        row_ptr[4 * w + 3] = ex + r0 + r1 + r2;
    }
    if (t == 255) blockSums[blockIdx.x] = sB[255];
}

// ---- scan pass 2 -------------------------------------------------------------
__global__ __launch_bounds__(256) void k_scan2(unsigned* __restrict__ blockSums,
                                               unsigned* __restrict__ blockOff) {
    __shared__ unsigned s[256];
    int t = threadIdx.x;
    unsigned val = (t < NBR) ? blockSums[t] : 0u;
    s[t] = val;
    __syncthreads();
    for (int off = 1; off < 256; off <<= 1) {
        unsigned x = (t >= off) ? s[t - off] : 0u;
        __syncthreads();
        s[t] += x;
        __syncthreads();
    }
    if (t < NBR) blockOff[t] = s[t] - val;
}

// ---- prescale: sfeat[n] = fp16(feat[n] * outnorm[n]) ------------------------
__global__ __launch_bounds__(256) void k_prescale(const float* __restrict__ feat,
                                                  const float* __restrict__ outnorm,
                                                  _Float16* __restrict__ sfeat) {
    int i = blockIdx.x * 256 + threadIdx.x;      // one thread per 8 elements
    if (i >= N_NODES * DIM / 8) return;
    int n = i >> 4;
    int d = (i & 15) << 3;
    float nrm = outnorm[n];
    const float4* p = reinterpret_cast<const float4*>(feat + (size_t)n * DIM + d);
    float4 a = p[0], q = p[1];
    h8 r;
    r[0] = (_Float16)(a.x * nrm); r[1] = (_Float16)(a.y * nrm);
    r[2] = (_Float16)(a.z * nrm); r[3] = (_Float16)(a.w * nrm);
    r[4] = (_Float16)(q.x * nrm); r[5] = (_Float16)(q.y * nrm);
    r[6] = (_Float16)(q.z * nrm); r[7] = (_Float16)(q.w * nrm);
    *reinterpret_cast<h8*>(sfeat + (size_t)n * DIM + d) = r;
}

// ---- place edges into CSR buckets — pure streaming, zero atomics ------------
__global__ __launch_bounds__(256) void k_place(const int* __restrict__ src,
                                               const int* __restrict__ dst,
                                               const unsigned* __restrict__ Hin,
                                               const unsigned char* __restrict__ perm,
                                               const unsigned* __restrict__ row_ptr,
                                               const unsigned* __restrict__ blockOff,
                                               int* __restrict__ bsrc) {
    int c = blockIdx.y;
    int i = blockIdx.x * 256 + threadIdx.x;
    if (i >= CSZ) return;
    int e = c * CSZ + i;
    int d = dst[e];
    int sh = (d & 3) * 8;
    unsigned pre = (Hin[(size_t)c * LQ + (d >> 2)] >> sh) & 0xffu;
    unsigned pos = row_ptr[d] + blockOff[d >> 10] + pre + perm[e];
    bsrc[pos] = src[e];
}

#define CVT8(ACC_A, ACC_B, R, M) \
    ACC_A.x += (M) * (float)R[0]; ACC_A.y += (M) * (float)R[1]; \
    ACC_A.z += (M) * (float)R[2]; ACC_A.w += (M) * (float)R[3]; \
    ACC_B.x += (M) * (float)R[4]; ACC_B.y += (M) * (float)R[5]; \
    ACC_B.z += (M) * (float)R[6]; ACC_B.w += (M) * (float)R[7];

// ---- gather-sum over fp16 prescaled rows: quarter-wave per edge -------------
// 16 lanes x 8 dims (16B) per row; 8 edge rows per wave-iteration.
__global__ __launch_bounds__(256) void k_gather(const int* __restrict__ bsrc,
                                                const unsigned* __restrict__ row_ptr,
                                                const unsigned* __restrict__ blockOff,
                                                const unsigned* __restrict__ indeg,
                                                const _Float16* __restrict__ sfeat,
                                                const float* __restrict__ innorm,
                                                float* __restrict__ agg) {
    int tid = threadIdx.x;
    int wave = tid >> 6;
    int lane = tid & 63;
    int node = blockIdx.x * 4 + wave;
    if (node >= N_NODES) return;
    unsigned start = row_ptr[node] + blockOff[node >> 10];
    unsigned deg   = indeg[node];
    unsigned lim   = deg < 64u ? deg : 64u;
    int qtr = lane >> 4;           // 0..3
    int d8  = (lane & 15) << 3;    // dim base, 8 dims/lane
    int sIdx = 0;
    if ((unsigned)lane < lim) sIdx = bsrc[start + lane];
    float4 accA = {0,0,0,0}, accB = {0,0,0,0};
    for (unsigned j = 0; j < lim; j += 8) {
        unsigned j0 = j + qtr, j1 = j + 4 + qtr;
        int   s0 = __shfl(sIdx, (int)(j0 < lim ? j0 : 0u));
        int   s1 = __shfl(sIdx, (int)(j1 < lim ? j1 : 0u));
        float m0 = (j0 < lim) ? 1.f : 0.f;
        float m1 = (j1 < lim) ? 1.f : 0.f;
        h8 r0 = *reinterpret_cast<const h8*>(sfeat + (size_t)s0 * DIM + d8);
        h8 r1 = *reinterpret_cast<const h8*>(sfeat + (size_t)s1 * DIM + d8);
        CVT8(accA, accB, r0, m0);
        CVT8(accA, accB, r1, m1);
    }
    for (unsigned j = 64; j < deg; j += 4) {   // overflow: deg > 64
        unsigned jj = j + qtr;
        bool valid = jj < deg;
        int s = bsrc[start + (valid ? jj : 0u)];
        float m = valid ? 1.f : 0.f;
        h8 r = *reinterpret_cast<const h8*>(sfeat + (size_t)s * DIM + d8);
        CVT8(accA, accB, r, m);
    }
    // reduce across quarters (lanes l, l+16, l+32, l+48)
    accA.x += __shfl_down(accA.x, 32); accA.y += __shfl_down(accA.y, 32);
    accA.z += __shfl_down(accA.z, 32); accA.w += __shfl_down(accA.w, 32);
    accB.x += __shfl_down(accB.x, 32); accB.y += __shfl_down(accB.y, 32);
    accB.z += __shfl_down(accB.z, 32); accB.w += __shfl_down(accB.w, 32);
    accA.x += __shfl_down(accA.x, 16); accA.y += __shfl_down(accA.y, 16);
    accA.z += __shfl_down(accA.z, 16); accA.w += __shfl_down(accA.w, 16);
    accB.x += __shfl_down(accB.x, 16); accB.y += __shfl_down(accB.y, 16);
    accB.z += __shfl_down(accB.z, 16); accB.w += __shfl_down(accB.w, 16);
    if (qtr == 0) {
        float innrm = innorm[node];
        float4 ra = {accA.x * innrm, accA.y * innrm, accA.z * innrm, accA.w * innrm};
        float4 rb = {accB.x * innrm, accB.y * innrm, accB.z * innrm, accB.w * innrm};
        float* ap = agg + (size_t)node * DIM + d8;
        *reinterpret_cast<float4*>(ap)     = ra;
        *reinterpret_cast<float4*>(ap + 4) = rb;
    }
}

#define FMA4(ACC, S, WV) ACC.x += (S) * WV.x; ACC.y += (S) * WV.y; \
                         ACC.z += (S) * WV.z; ACC.w += (S) * WV.w;

// ---- node transform: h = relu(agg @ W + b), in place. 4 nodes x 4 outs/thread
__global__ __launch_bounds__(256) void k_node(float* __restrict__ agg,
                                              const float* __restrict__ W,
                                              const float* __restrict__ b) {
    __shared__ float sW[DIM * DIM];        // 64 KB
    __shared__ float srow[PASSN][DIM];     // 16 KB
    int tid = threadIdx.x;
    for (int i = tid; i < DIM * DIM; i += 256) sW[i] = W[i];

    int o  = (tid & 31) << 2;
    int n0 = (tid >> 5) << 2;
    float4 bb = *reinterpret_cast<const float4*>(b + o);

    int blockBase = blockIdx.x * NPB;
    for (int p = 0; p < NPB / PASSN; ++p) {
        int base = blockBase + p * PASSN;
        __syncthreads();
        for (int i = tid; i < PASSN * 32; i += 256) {
            int n = i >> 5, d4 = (i & 31) << 2;
            int node = base + n;
            float4 v = {0.f, 0.f, 0.f, 0.f};
            if (node < N_NODES)
                v = *reinterpret_cast<const float4*>(agg + (size_t)node * DIM + d4);
            *reinterpret_cast<float4*>(&srow[n][d4]) = v;
        }
        __syncthreads();
        float4 acc0 = {0,0,0,0}, acc1 = {0,0,0,0}, acc2 = {0,0,0,0}, acc3 = {0,0,0,0};
#pragma unroll 4
        for (int k = 0; k < DIM; k += 4) {
            float4 w0 = *reinterpret_cast<const float4*>(&sW[(k + 0) * DIM + o]);
            float4 w1 = *reinterpret_cast<const float4*>(&sW[(k + 1) * DIM + o]);
            float4 w2 = *reinterpret_cast<const float4*>(&sW[(k + 2) * DIM + o]);
            float4 w3 = *reinterpret_cast<const float4*>(&sW[(k + 3) * DIM + o]);
            float4 a0 = *reinterpret_cast<const float4*>(&srow[n0 + 0][k]);
            float4 a1 = *reinterpret_cast<const float4*>(&srow[n0 + 1][k]);
            float4 a2 = *reinterpret_cast<const float4*>(&srow[n0 + 2][k]);
            float4 a3 = *reinterpret_cast<const float4*>(&srow[n0 + 3][k]);
            FMA4(acc0, a0.x, w0); FMA4(acc0, a0.y, w1); FMA4(acc0, a0.z, w2); FMA4(acc0, a0.w, w3);
            FMA4(acc1, a1.x, w0); FMA4(acc1, a1.y, w1); FMA4(acc1, a1.z, w2); FMA4(acc1, a1.w, w3);
            FMA4(acc2, a2.x, w0); FMA4(acc2, a2.y, w1); FMA4(acc2, a2.z, w2); FMA4(acc2, a2.w, w3);
            FMA4(acc3, a3.x, w0); FMA4(acc3, a3.y, w1); FMA4(acc3, a3.z, w2); FMA4(acc3, a3.w, w3);
        }
        __syncthreads();
        float4 accs[4] = {acc0, acc1, acc2, acc3};
#pragma unroll
        for (int j = 0; j < 4; ++j) {
            int node = base + n0 + j;
            if (node < N_NODES) {
                float4 h;
                h.x = fmaxf(accs[j].x + bb.x, 0.0f);
                h.y = fmaxf(accs[j].y + bb.y, 0.0f);
                h.z = fmaxf(accs[j].z + bb.z, 0.0f);
                h.w = fmaxf(accs[j].w + bb.w, 0.0f);
                *reinterpret_cast<float4*>(agg + (size_t)node * DIM + o) = h;
            }
        }
    }
}

// ---- graph sum-pool, parallel: grid (G, NCHUNK); atomics into zeroed pooled -
__global__ __launch_bounds__(256) void k_pool(const float* __restrict__ h,
                                              const int* __restrict__ start,
                                              float* __restrict__ pooled) {
    __shared__ float red[8][DIM];
    int g = blockIdx.x;
    int chunk = blockIdx.y;
    int t = threadIdx.x;
    int slot = t >> 5;
    int q    = (t & 31) << 2;
    int s = start[g], e = start[g + 1];
    float4 acc = {0.f, 0.f, 0.f, 0.f};
    for (int n = s + chunk * 8 + slot; n < e; n += NCHUNK * 8) {
        float4 v = *reinterpret_cast<const float4*>(h + (size_t)n * DIM + q);
        acc.x += v.x; acc.y += v.y; acc.z += v.z; acc.w += v.w;
    }
    *reinterpret_cast<float4*>(&red[slot][q]) = acc;
    __syncthreads();
    if (t < DIM) {
        float sum = 0.f;
#pragma unroll
        for (int r = 0; r < 8; ++r) sum += red[r][t];
        atomicAdd(&pooled[g * DIM + t], sum);
    }
}

// ---- head: out = (pooled/cnt) @ W_head + b_head -----------------------------
__global__ __launch_bounds__(256) void k_head(const float* __restrict__ pooled,
                                              const int* __restrict__ start,
                                              const float* __restrict__ Wh,
                                              const float* __restrict__ bh,
                                              float* __restrict__ out) {
    int i = blockIdx.x * 256 + threadIdx.x;
    if (i >= N_GRAPHS * N_CLASSES) return;
    int g = i / N_CLASSES, c = i % N_CLASSES;
    const float* pr = pooled + g * DIM;
    float s = 0.f;
#pragma unroll 8
    for (int k = 0; k < DIM; ++k) s += pr[k] * Wh[k * N_CLASSES + c];
    float cntf = fmaxf((float)(start[g + 1] - start[g]), 1.0f);
    out[i] = s / cntf + bh[c];
}

extern "C" void kernel_launch(void* const* d_in, const int* in_sizes, int n_in,
                              void* d_out, int out_size, void* d_ws, size_t ws_size,
                              hipStream_t stream) {
    const float* feat = (const float*)d_in[0];
    const int*   src  = (const int*)d_in[1];
    const int*   dst  = (const int*)d_in[2];
    const int*   gid  = (const int*)d_in[3];
    const float* W    = (const float*)d_in[4];
    const float* b    = (const float*)d_in[5];
    const float* Wh   = (const float*)d_in[6];
    const float* bh   = (const float*)d_in[7];
    float* out = (float*)d_out;

    // ---- workspace layout (4-byte elements) ----
    float*    pooled   = (float*)d_ws;                                  // G*D (zeroed)
    unsigned* indeg    = (unsigned*)(pooled + (size_t)N_GRAPHS * DIM);  // N
    float*    outnorm  = (float*)(indeg + N_NODES);                     // N
    float*    innorm   = outnorm + N_NODES;                             // N
    int*      start    = (int*)(innorm + N_NODES);                      // G+1
    unsigned* row_ptr  = (unsigned*)(start + N_GRAPHS + 1);             // N
    unsigned* blockSums= row_ptr + N_NODES;                             // 256
    unsigned* blockOff = blockSums + 256;                               // 256
    unsigned char* perm= (unsigned char*)(blockOff + 256);              // E bytes
    int*      bsrc     = (int*)(perm + N_EDGES);                        // E
    _Float16* sfeat    = (_Float16*)(bsrc + N_EDGES);                   // N*D halves
    float*    agg      = (float*)(sfeat + (size_t)N_NODES * DIM);       // N*D (reused as h)
    // Hin/Hout alias agg (2*NCHE*LQ words == N*DIM exactly); consumed before k_gather
    unsigned* Hin      = (unsigned*)agg;                                // NCHE*LQ
    unsigned* Hout     = Hin + (size_t)NCHE * LQ;                       // NCHE*LQ

    hipMemsetAsync(pooled, 0, (size_t)N_GRAPHS * DIM * 4, stream);

    k_lhist   <<<NCHE, 256, 0, stream>>>(src, dst, Hin, Hout, perm);
    k_reduce  <<<NBR, 256, 0, stream>>>(Hin, Hout, gid, indeg, outnorm, innorm,
                                        start, row_ptr, blockSums);
    k_scan2   <<<1, 256, 0, stream>>>(blockSums, blockOff);
    k_prescale<<<(N_NODES * DIM / 8 + 255) / 256, 256, 0, stream>>>(feat, outnorm, sfeat);
    dim3 pgp((CSZ + 255) / 256, NCHE);
    k_place   <<<pgp, 256, 0, stream>>>(src, dst, Hin, perm, row_ptr, blockOff, bsrc);
    k_gather  <<<(N_NODES + 3) / 4, 256, 0, stream>>>(bsrc, row_ptr, blockOff, indeg,
                                                      sfeat, innorm, agg);
    k_node    <<<(N_NODES + NPB - 1) / NPB, 256, 0, stream>>>(agg, W, b);
    dim3 pg(N_GRAPHS, NCHUNK);
    k_pool    <<<pg, 256, 0, stream>>>(agg, start, pooled);
    k_head    <<<3, 256, 0, stream>>>(pooled, start, Wh, bh, out);
}

// Round 10
// 234.748 us; speedup vs baseline: 1.2752x; 1.0605x over previous
//
#include <hip/hip_runtime.h>

#define N_NODES   50000
#define N_EDGES   800000
#define DIM       128
#define N_GRAPHS  64
#define N_CLASSES 10
#define NPB       128                  // nodes per block in k_node
#define PASSN     32                   // nodes staged per pass in k_node
#define NCHE      256                  // edge chunks
#define CSZ       (N_EDGES / NCHE)     // 3125
#define LQ        (N_NODES / 4)        // 12500 u8-packed words (4 nodes/word)
#define WPB       64                   // words per reduce block (256 nodes)
#define NBR2      ((LQ + WPB - 1) / WPB)   // 196
#define PLACE_BPC ((CSZ + 255) / 256)      // 13
#define PLACE_BLKS (NCHE * PLACE_BPC)      // 3328
#define PRES_BLKS ((N_NODES * DIM / 8 + 255) / 256)  // 3125

typedef _Float16 h8 __attribute__((ext_vector_type(8)));

// ---- per-chunk LDS histograms (u8 packed), dst/src phases in parallel blocks
__global__ __launch_bounds__(256) void k_lhist(const int* __restrict__ src,
                                               const int* __restrict__ dst,
                                               unsigned* __restrict__ Hin,
                                               unsigned* __restrict__ Hout,
                                               unsigned char* __restrict__ perm) {
    __shared__ unsigned L[LQ];         // 50 KB
    int c = blockIdx.x, t = threadIdx.x;
    int base = c * CSZ;
    for (int w = t; w < LQ; w += 256) L[w] = 0u;
    __syncthreads();
    if (blockIdx.y == 0) {
        for (int i = t; i < CSZ; i += 256) {
            int d = dst[base + i];
            int sh = (d & 3) * 8;
            unsigned old = atomicAdd(&L[d >> 2], 1u << sh);
            perm[base + i] = (unsigned char)((old >> sh) & 0xffu);
        }
        __syncthreads();
        for (int w = t; w < LQ; w += 256) Hin[(size_t)c * LQ + w] = L[w];
    } else {
        for (int i = t; i < CSZ; i += 256) {
            int s = src[base + i];
            atomicAdd(&L[s >> 2], 1u << ((s & 3) * 8));
        }
        __syncthreads();
        for (int w = t; w < LQ; w += 256) Hout[(size_t)c * LQ + w] = L[w];
    }
}

// ---- reduce v2: 196 blocks, 4 chunk-groups/word; Hin := per-chunk prefix; ---
// degrees/norms, graph boundaries, fused scan pass 1 (256 nodes/block)
__global__ __launch_bounds__(256) void k_reduce(unsigned* __restrict__ Hin,
                                                const unsigned* __restrict__ Hout,
                                                const int* __restrict__ gid,
                                                unsigned* __restrict__ indeg,
                                                float* __restrict__ outnorm,
                                                float* __restrict__ innorm,
                                                int* __restrict__ start,
                                                unsigned* __restrict__ row_ptr,
                                                unsigned* __restrict__ blockSums) {
    __shared__ unsigned sIn[4][WPB];
    __shared__ unsigned sOut[4][WPB];
    __shared__ unsigned sS[WPB];
    int t = threadIdx.x;
    int wl = t & (WPB - 1);
    int g  = t >> 6;                   // chunk-group 0..3
    int w  = blockIdx.x * WPB + wl;
    unsigned gs = 0, os = 0;
    int c0 = g * (NCHE / 4);
    if (w < LQ) {
        for (int c = c0; c < c0 + NCHE / 4; ++c) {
            gs += Hin[(size_t)c * LQ + w];     // packed u8 adds: no carry (deg<=~50)
            os += Hout[(size_t)c * LQ + w];
        }
    }
    sIn[g][wl] = gs; sOut[g][wl] = os;
    __syncthreads();
    unsigned baseg = 0;
    for (int gg = 0; gg < 4; ++gg) if (gg < g) baseg += sIn[gg][wl];
    if (w < LQ) {
        unsigned running = baseg;
        for (int c = c0; c < c0 + NCHE / 4; ++c) {
            size_t idx = (size_t)c * LQ + w;
            unsigned word = Hin[idx];
            Hin[idx] = running;
            running += word;
        }
    }
    // finalize by t<64 (one thread per word)
    unsigned tot = 0, otot = 0, wtot = 0;
    if (t < WPB) {
        tot  = sIn[0][t] + sIn[1][t] + sIn[2][t] + sIn[3][t];
        otot = sOut[0][t] + sOut[1][t] + sOut[2][t] + sOut[3][t];
        wtot = (tot & 0xffu) + ((tot >> 8) & 0xffu) + ((tot >> 16) & 0xffu) + (tot >> 24);
        sS[t] = wtot;
    }
    __syncthreads();
    for (int off = 1; off < WPB; off <<= 1) {
        unsigned x = (t < WPB && t >= off) ? sS[t - off] : 0u;
        __syncthreads();
        if (t < WPB) sS[t] += x;
        __syncthreads();
    }
    if (t < WPB) {
        int ww = blockIdx.x * WPB + t;
        if (ww < LQ) {
            unsigned r0 = tot & 0xffu, r1 = (tot >> 8) & 0xffu,
                     r2 = (tot >> 16) & 0xffu, r3 = tot >> 24;
            unsigned o0 = otot & 0xffu, o1 = (otot >> 8) & 0xffu,
                     o2 = (otot >> 16) & 0xffu, o3 = otot >> 24;
            unsigned ex = sS[t] - wtot;
            int n = 4 * ww;
            row_ptr[n]     = ex;
            row_ptr[n + 1] = ex + r0;
            row_ptr[n + 2] = ex + r0 + r1;
            row_ptr[n + 3] = ex + r0 + r1 + r2;
            unsigned rr[4] = {r0, r1, r2, r3}, oo[4] = {o0, o1, o2, o3};
#pragma unroll
            for (int j = 0; j < 4; ++j) {
                indeg[n + j]   = rr[j];
                innorm[n + j]  = rsqrtf(fmaxf((float)rr[j], 1.0f));
                outnorm[n + j] = rsqrtf(fmaxf((float)oo[j], 1.0f));
                int i = n + j;
                int gq = gid[i];
                if (i == 0) {
                    for (int x2 = 0; x2 <= gq; ++x2) start[x2] = 0;
                } else {
                    int gp = gid[i - 1];
                    if (gp != gq)
                        for (int x2 = gp + 1; x2 <= gq; ++x2) start[x2] = i;
                }
                if (i == N_NODES - 1)
                    for (int x2 = gq + 1; x2 <= N_GRAPHS; ++x2) start[x2] = N_NODES;
            }
        }
        if (t == WPB - 1) blockSums[blockIdx.x] = sS[WPB - 1];
    }
}

// ---- scan pass 2 over NBR2 block sums ---------------------------------------
__global__ __launch_bounds__(256) void k_scan2(unsigned* __restrict__ blockSums,
                                               unsigned* __restrict__ blockOff) {
    __shared__ unsigned s[256];
    int t = threadIdx.x;
    unsigned val = (t < NBR2) ? blockSums[t] : 0u;
    s[t] = val;
    __syncthreads();
    for (int off = 1; off < 256; off <<= 1) {
        unsigned x = (t >= off) ? s[t - off] : 0u;
        __syncthreads();
        s[t] += x;
        __syncthreads();
    }
    if (t < NBR2) blockOff[t] = s[t] - val;
}

// ---- fused: CSR place (streaming, no atomics) + fp16 prescale ---------------
__global__ __launch_bounds__(256) void k_prep(const int* __restrict__ src,
                                              const int* __restrict__ dst,
                                              const unsigned* __restrict__ Hin,
                                              const unsigned char* __restrict__ perm,
                                              const unsigned* __restrict__ row_ptr,
                                              const unsigned* __restrict__ blockOff,
                                              int* __restrict__ bsrc,
                                              const float* __restrict__ feat,
                                              const float* __restrict__ outnorm,
                                              _Float16* __restrict__ sfeat) {
    int t = threadIdx.x;
    int blk = blockIdx.x;
    if (blk < PLACE_BLKS) {
        int c = blk / PLACE_BPC;
        int i = (blk % PLACE_BPC) * 256 + t;
        if (i < CSZ) {
            int e = c * CSZ + i;
            int d = dst[e];
            int sh = (d & 3) * 8;
            unsigned pre = (Hin[(size_t)c * LQ + (d >> 2)] >> sh) & 0xffu;
            unsigned pos = row_ptr[d] + blockOff[d >> 8] + pre + perm[e];
            bsrc[pos] = src[e];
        }
    } else {
        int i = (blk - PLACE_BLKS) * 256 + t;
        if (i < N_NODES * DIM / 8) {
            int n = i >> 4;
            int d = (i & 15) << 3;
            float nrm = outnorm[n];
            const float4* p = reinterpret_cast<const float4*>(feat + (size_t)n * DIM + d);
            float4 a = p[0], q = p[1];
            h8 r;
            r[0] = (_Float16)(a.x * nrm); r[1] = (_Float16)(a.y * nrm);
            r[2] = (_Float16)(a.z * nrm); r[3] = (_Float16)(a.w * nrm);
            r[4] = (_Float16)(q.x * nrm); r[5] = (_Float16)(q.y * nrm);
            r[6] = (_Float16)(q.z * nrm); r[7] = (_Float16)(q.w * nrm);
            *reinterpret_cast<h8*>(sfeat + (size_t)n * DIM + d) = r;
        }
    }
}

#define CVT8(ACC_A, ACC_B, R, M) \
    ACC_A.x += (M) * (float)R[0]; ACC_A.y += (M) * (float)R[1]; \
    ACC_A.z += (M) * (float)R[2]; ACC_A.w += (M) * (float)R[3]; \
    ACC_B.x += (M) * (float)R[4]; ACC_B.y += (M) * (float)R[5]; \
    ACC_B.z += (M) * (float)R[6]; ACC_B.w += (M) * (float)R[7];

// ---- gather-sum over fp16 prescaled rows: quarter-wave per edge -------------
__global__ __launch_bounds__(256) void k_gather(const int* __restrict__ bsrc,
                                                const unsigned* __restrict__ row_ptr,
                                                const unsigned* __restrict__ blockOff,
                                                const unsigned* __restrict__ indeg,
                                                const _Float16* __restrict__ sfeat,
                                                const float* __restrict__ innorm,
                                                float* __restrict__ agg) {
    int tid = threadIdx.x;
    int wave = tid >> 6;
    int lane = tid & 63;
    int node = blockIdx.x * 4 + wave;
    if (node >= N_NODES) return;
    unsigned start = row_ptr[node] + blockOff[node >> 8];
    unsigned deg   = indeg[node];
    unsigned lim   = deg < 64u ? deg : 64u;
    int qtr = lane >> 4;
    int d8  = (lane & 15) << 3;
    int sIdx = 0;
    if ((unsigned)lane < lim) sIdx = bsrc[start + lane];
    float4 accA = {0,0,0,0}, accB = {0,0,0,0};
    for (unsigned j = 0; j < lim; j += 8) {
        unsigned j0 = j + qtr, j1 = j + 4 + qtr;
        int   s0 = __shfl(sIdx, (int)(j0 < lim ? j0 : 0u));
        int   s1 = __shfl(sIdx, (int)(j1 < lim ? j1 : 0u));
        float m0 = (j0 < lim) ? 1.f : 0.f;
        float m1 = (j1 < lim) ? 1.f : 0.f;
        h8 r0 = *reinterpret_cast<const h8*>(sfeat + (size_t)s0 * DIM + d8);
        h8 r1 = *reinterpret_cast<const h8*>(sfeat + (size_t)s1 * DIM + d8);
        CVT8(accA, accB, r0, m0);
        CVT8(accA, accB, r1, m1);
    }
    for (unsigned j = 64; j < deg; j += 4) {
        unsigned jj = j + qtr;
        bool valid = jj < deg;
        int s = bsrc[start + (valid ? jj : 0u)];
        float m = valid ? 1.f : 0.f;
        h8 r = *reinterpret_cast<const h8*>(sfeat + (size_t)s * DIM + d8);
        CVT8(accA, accB, r, m);
    }
    accA.x += __shfl_down(accA.x, 32); accA.y += __shfl_down(accA.y, 32);
    accA.z += __shfl_down(accA.z, 32); accA.w += __shfl_down(accA.w, 32);
    accB.x += __shfl_down(accB.x, 32); accB.y += __shfl_down(accB.y, 32);
    accB.z += __shfl_down(accB.z, 32); accB.w += __shfl_down(accB.w, 32);
    accA.x += __shfl_down(accA.x, 16); accA.y += __shfl_down(accA.y, 16);
    accA.z += __shfl_down(accA.z, 16); accA.w += __shfl_down(accA.w, 16);
    accB.x += __shfl_down(accB.x, 16); accB.y += __shfl_down(accB.y, 16);
    accB.z += __shfl_down(accB.z, 16); accB.w += __shfl_down(accB.w, 16);
    if (qtr == 0) {
        float innrm = innorm[node];
        float4 ra = {accA.x * innrm, accA.y * innrm, accA.z * innrm, accA.w * innrm};
        float4 rb = {accB.x * innrm, accB.y * innrm, accB.z * innrm, accB.w * innrm};
        float* ap = agg + (size_t)node * DIM + d8;
        *reinterpret_cast<float4*>(ap)     = ra;
        *reinterpret_cast<float4*>(ap + 4) = rb;
    }
}

#define FMA4(ACC, S, WV) ACC.x += (S) * WV.x; ACC.y += (S) * WV.y; \
                         ACC.z += (S) * WV.z; ACC.w += (S) * WV.w;

// ---- node transform + fused mean-pool: h = relu(agg@W+b) pooled per graph ---
// 4 nodes x 4 outs/thread; per-graph register accumulators (128-node block
// spans <=2 graphs; fallback atomics cover pathological spans), LDS-reduced
// at epilogue, ~128 global atomics per (block,graph). h never hits HBM.
__global__ __launch_bounds__(256) void k_node(const float* __restrict__ agg,
                                              const int* __restrict__ gid,
                                              const float* __restrict__ W,
                                              const float* __restrict__ b,
                                              float* __restrict__ pooled) {
    __shared__ float sW[DIM * DIM];        // 64 KB
    __shared__ float srow[PASSN][DIM];     // 16 KB (aliased as red[] at epilogue)
    int tid = threadIdx.x;
    for (int i = tid; i < DIM * DIM; i += 256) sW[i] = W[i];

    int o  = (tid & 31) << 2;
    int n0 = (tid >> 5) << 2;
    float4 bb = *reinterpret_cast<const float4*>(b + o);
    int blockBase = blockIdx.x * NPB;
    int gfirst = gid[blockBase];
    float4 racc[4];
    racc[0] = racc[1] = racc[2] = racc[3] = float4{0.f, 0.f, 0.f, 0.f};

    for (int p = 0; p < NPB / PASSN; ++p) {
        int base = blockBase + p * PASSN;
        __syncthreads();
        for (int i = tid; i < PASSN * 32; i += 256) {
            int n = i >> 5, d4 = (i & 31) << 2;
            int node = base + n;
            float4 v = {0.f, 0.f, 0.f, 0.f};
            if (node < N_NODES)
                v = *reinterpret_cast<const float4*>(agg + (size_t)node * DIM + d4);
            *reinterpret_cast<float4*>(&srow[n][d4]) = v;
        }
        __syncthreads();
        float4 acc0 = {0,0,0,0}, acc1 = {0,0,0,0}, acc2 = {0,0,0,0}, acc3 = {0,0,0,0};
#pragma unroll 4
        for (int k = 0; k < DIM; k += 4) {
            float4 w0 = *reinterpret_cast<const float4*>(&sW[(k + 0) * DIM + o]);
            float4 w1 = *reinterpret_cast<const float4*>(&sW[(k + 1) * DIM + o]);
            float4 w2 = *reinterpret_cast<const float4*>(&sW[(k + 2) * DIM + o]);
            float4 w3 = *reinterpret_cast<const float4*>(&sW[(k + 3) * DIM + o]);
            float4 a0 = *reinterpret_cast<const float4*>(&srow[n0 + 0][k]);
            float4 a1 = *reinterpret_cast<const float4*>(&srow[n0 + 1][k]);
            float4 a2 = *reinterpret_cast<const float4*>(&srow[n0 + 2][k]);
            float4 a3 = *reinterpret_cast<const float4*>(&srow[n0 + 3][k]);
            FMA4(acc0, a0.x, w0); FMA4(acc0, a0.y, w1); FMA4(acc0, a0.z, w2); FMA4(acc0, a0.w, w3);
            FMA4(acc1, a1.x, w0); FMA4(acc1, a1.y, w1); FMA4(acc1, a1.z, w2); FMA4(acc1, a1.w, w3);
            FMA4(acc2, a2.x, w0); FMA4(acc2, a2.y, w1); FMA4(acc2, a2.z, w2); FMA4(acc2, a2.w, w3);
            FMA4(acc3, a3.x, w0); FMA4(acc3, a3.y, w1); FMA4(acc3, a3.z, w2); FMA4(acc3, a3.w, w3);
        }
        float4 accs[4] = {acc0, acc1, acc2, acc3};
#pragma unroll
        for (int j = 0; j < 4; ++j) {
            int node = base + n0 + j;
            if (node < N_NODES) {
                float4 h;
                h.x = fmaxf(accs[j].x + bb.x, 0.0f);
                h.y = fmaxf(accs[j].y + bb.y, 0.0f);
                h.z = fmaxf(accs[j].z + bb.z, 0.0f);
                h.w = fmaxf(accs[j].w + bb.w, 0.0f);
                int gg = gid[node] - gfirst;
                if (gg >= 0 && gg < 4) {
                    racc[gg].x += h.x; racc[gg].y += h.y;
                    racc[gg].z += h.z; racc[gg].w += h.w;
                } else {  // pathological span: direct atomics (never for this graph)
                    float* pp = pooled + (size_t)gid[node] * DIM + o;
                    atomicAdd(pp + 0, h.x); atomicAdd(pp + 1, h.y);
                    atomicAdd(pp + 2, h.z); atomicAdd(pp + 3, h.w);
                }
            }
        }
    }
    // epilogue: reduce 8 node-slots per output lane, atomics into pooled
    float* red = (float*)srow;             // [8][DIM]
    int slot = tid >> 5;
    for (int a = 0; a < 4; ++a) {
        __syncthreads();
        *reinterpret_cast<float4*>(&red[slot * DIM + o]) = racc[a];
        __syncthreads();
        if (tid < DIM) {
            float s = 0.f;
#pragma unroll
            for (int r = 0; r < 8; ++r) s += red[r * DIM + tid];
            int gdst = gfirst + a;
            if (s != 0.f && gdst < N_GRAPHS)
                atomicAdd(&pooled[gdst * DIM + tid], s);
        }
    }
}

// ---- head: out = (pooled/cnt) @ W_head + b_head -----------------------------
__global__ __launch_bounds__(256) void k_head(const float* __restrict__ pooled,
                                              const int* __restrict__ start,
                                              const float* __restrict__ Wh,
                                              const float* __restrict__ bh,
                                              float* __restrict__ out) {
    int i = blockIdx.x * 256 + threadIdx.x;
    if (i >= N_GRAPHS * N_CLASSES) return;
    int g = i / N_CLASSES, c = i % N_CLASSES;
    const float* pr = pooled + g * DIM;
    float s = 0.f;
#pragma unroll 8
    for (int k = 0; k < DIM; ++k) s += pr[k] * Wh[k * N_CLASSES + c];
    float cntf = fmaxf((float)(start[g + 1] - start[g]), 1.0f);
    out[i] = s / cntf + bh[c];
}

extern "C" void kernel_launch(void* const* d_in, const int* in_sizes, int n_in,
                              void* d_out, int out_size, void* d_ws, size_t ws_size,
                              hipStream_t stream) {
    const float* feat = (const float*)d_in[0];
    const int*   src  = (const int*)d_in[1];
    const int*   dst  = (const int*)d_in[2];
    const int*   gid  = (const int*)d_in[3];
    const float* W    = (const float*)d_in[4];
    const float* b    = (const float*)d_in[5];
    const float* Wh   = (const float*)d_in[6];
    const float* bh   = (const float*)d_in[7];
    float* out = (float*)d_out;

    // ---- workspace layout (4-byte elements) ----
    float*    pooled   = (float*)d_ws;                                  // G*D (zeroed)
    unsigned* indeg    = (unsigned*)(pooled + (size_t)N_GRAPHS * DIM);  // N
    float*    outnorm  = (float*)(indeg + N_NODES);                     // N
    float*    innorm   = outnorm + N_NODES;                             // N
    int*      start    = (int*)(innorm + N_NODES);                      // G+1
    unsigned* row_ptr  = (unsigned*)(start + N_GRAPHS + 1);             // N
    unsigned* blockSums= row_ptr + N_NODES;                             // 256
    unsigned* blockOff = blockSums + 256;                               // 256
    unsigned char* perm= (unsigned char*)(blockOff + 256);              // E bytes
    int*      bsrc     = (int*)(perm + N_EDGES);                        // E
    _Float16* sfeat    = (_Float16*)(bsrc + N_EDGES);                   // N*D halves
    float*    agg      = (float*)(sfeat + (size_t)N_NODES * DIM);       // N*D
    // Hin/Hout alias agg (2*NCHE*LQ words == N*DIM); consumed before k_gather
    unsigned* Hin      = (unsigned*)agg;                                // NCHE*LQ
    unsigned* Hout     = Hin + (size_t)NCHE * LQ;                       // NCHE*LQ

    hipMemsetAsync(pooled, 0, (size_t)N_GRAPHS * DIM * 4, stream);

    dim3 lh(NCHE, 2);
    k_lhist <<<lh, 256, 0, stream>>>(src, dst, Hin, Hout, perm);
    k_reduce<<<NBR2, 256, 0, stream>>>(Hin, Hout, gid, indeg, outnorm, innorm,
                                       start, row_ptr, blockSums);
    k_scan2 <<<1, 256, 0, stream>>>(blockSums, blockOff);
    k_prep  <<<PLACE_BLKS + PRES_BLKS, 256, 0, stream>>>(src, dst, Hin, perm, row_ptr,
                                                         blockOff, bsrc, feat, outnorm, sfeat);
    k_gather<<<(N_NODES + 3) / 4, 256, 0, stream>>>(bsrc, row_ptr, blockOff, indeg,
                                                    sfeat, innorm, agg);
    k_node  <<<(N_NODES + NPB - 1) / NPB, 256, 0, stream>>>(agg, gid, W, b, pooled);
    k_head  <<<3, 256, 0, stream>>>(pooled, start, Wh, bh, out);
}

// Round 11
// 206.830 us; speedup vs baseline: 1.4473x; 1.1350x over previous
//
#include <hip/hip_runtime.h>

#define N_NODES   50000
#define N_EDGES   800000
#define DIM       128
#define N_GRAPHS  64
#define N_CLASSES 10
#define NCHE      256                  // edge chunks
#define CSZ       (N_EDGES / NCHE)     // 3125
#define LQ        (N_NODES / 4)        // 12500 u8-packed words (4 nodes/word)
#define WPB       64                   // words per reduce block (256 nodes)
#define NBR2      ((LQ + WPB - 1) / WPB)   // 196
#define PLACE_BPC ((CSZ + 255) / 256)      // 13
#define PLACE_BLKS (NCHE * PLACE_BPC)      // 3328
#define PRES_BLKS ((N_NODES * DIM / 8 + 255) / 256)  // 3125
#define WT_BLKS   (DIM * DIM / 256)        // 64
#define NPBM      128                  // nodes per block in k_node (MFMA)
#define NBLK_NODE ((N_NODES + NPBM - 1) / NPBM)  // 391

typedef _Float16 h8 __attribute__((ext_vector_type(8)));
typedef float f4v __attribute__((ext_vector_type(4)));

// ---- per-chunk LDS histograms (u8 packed), dst/src phases in parallel blocks
__global__ __launch_bounds__(256) void k_lhist(const int* __restrict__ src,
                                               const int* __restrict__ dst,
                                               unsigned* __restrict__ Hin,
                                               unsigned* __restrict__ Hout,
                                               unsigned char* __restrict__ perm) {
    __shared__ unsigned L[LQ];         // 50 KB
    int c = blockIdx.x, t = threadIdx.x;
    int base = c * CSZ;
    for (int w = t; w < LQ; w += 256) L[w] = 0u;
    __syncthreads();
    if (blockIdx.y == 0) {
        for (int i = t; i < CSZ; i += 256) {
            int d = dst[base + i];
            int sh = (d & 3) * 8;
            unsigned old = atomicAdd(&L[d >> 2], 1u << sh);
            perm[base + i] = (unsigned char)((old >> sh) & 0xffu);
        }
        __syncthreads();
        for (int w = t; w < LQ; w += 256) Hin[(size_t)c * LQ + w] = L[w];
    } else {
        for (int i = t; i < CSZ; i += 256) {
            int s = src[base + i];
            atomicAdd(&L[s >> 2], 1u << ((s & 3) * 8));
        }
        __syncthreads();
        for (int w = t; w < LQ; w += 256) Hout[(size_t)c * LQ + w] = L[w];
    }
}

// ---- reduce: degrees/norms; Hin := per-chunk prefix; boundaries; scan p1 ----
__global__ __launch_bounds__(256) void k_reduce(unsigned* __restrict__ Hin,
                                                const unsigned* __restrict__ Hout,
                                                const int* __restrict__ gid,
                                                unsigned* __restrict__ indeg,
                                                float* __restrict__ outnorm,
                                                float* __restrict__ innorm,
                                                int* __restrict__ start,
                                                unsigned* __restrict__ row_ptr,
                                                unsigned* __restrict__ blockSums) {
    __shared__ unsigned sIn[4][WPB];
    __shared__ unsigned sOut[4][WPB];
    __shared__ unsigned sS[WPB];
    int t = threadIdx.x;
    int wl = t & (WPB - 1);
    int g  = t >> 6;
    int w  = blockIdx.x * WPB + wl;
    unsigned gs = 0, os = 0;
    int c0 = g * (NCHE / 4);
    if (w < LQ) {
        for (int c = c0; c < c0 + NCHE / 4; ++c) {
            gs += Hin[(size_t)c * LQ + w];
            os += Hout[(size_t)c * LQ + w];
        }
    }
    sIn[g][wl] = gs; sOut[g][wl] = os;
    __syncthreads();
    unsigned baseg = 0;
    for (int gg = 0; gg < 4; ++gg) if (gg < g) baseg += sIn[gg][wl];
    if (w < LQ) {
        unsigned running = baseg;
        for (int c = c0; c < c0 + NCHE / 4; ++c) {
            size_t idx = (size_t)c * LQ + w;
            unsigned word = Hin[idx];
            Hin[idx] = running;
            running += word;
        }
    }
    unsigned tot = 0, otot = 0, wtot = 0;
    if (t < WPB) {
        tot  = sIn[0][t] + sIn[1][t] + sIn[2][t] + sIn[3][t];
        otot = sOut[0][t] + sOut[1][t] + sOut[2][t] + sOut[3][t];
        wtot = (tot & 0xffu) + ((tot >> 8) & 0xffu) + ((tot >> 16) & 0xffu) + (tot >> 24);
        sS[t] = wtot;
    }
    __syncthreads();
    for (int off = 1; off < WPB; off <<= 1) {
        unsigned x = (t < WPB && t >= off) ? sS[t - off] : 0u;
        __syncthreads();
        if (t < WPB) sS[t] += x;
        __syncthreads();
    }
    if (t < WPB) {
        int ww = blockIdx.x * WPB + t;
        if (ww < LQ) {
            unsigned r0 = tot & 0xffu, r1 = (tot >> 8) & 0xffu,
                     r2 = (tot >> 16) & 0xffu, r3 = tot >> 24;
            unsigned o0 = otot & 0xffu, o1 = (otot >> 8) & 0xffu,
                     o2 = (otot >> 16) & 0xffu, o3 = otot >> 24;
            unsigned ex = sS[t] - wtot;
            int n = 4 * ww;
            row_ptr[n]     = ex;
            row_ptr[n + 1] = ex + r0;
            row_ptr[n + 2] = ex + r0 + r1;
            row_ptr[n + 3] = ex + r0 + r1 + r2;
            unsigned rr[4] = {r0, r1, r2, r3}, oo[4] = {o0, o1, o2, o3};
#pragma unroll
            for (int j = 0; j < 4; ++j) {
                indeg[n + j]   = rr[j];
                innorm[n + j]  = rsqrtf(fmaxf((float)rr[j], 1.0f));
                outnorm[n + j] = rsqrtf(fmaxf((float)oo[j], 1.0f));
                int i = n + j;
                int gq = gid[i];
                if (i == 0) {
                    for (int x2 = 0; x2 <= gq; ++x2) start[x2] = 0;
                } else {
                    int gp = gid[i - 1];
                    if (gp != gq)
                        for (int x2 = gp + 1; x2 <= gq; ++x2) start[x2] = i;
                }
                if (i == N_NODES - 1)
                    for (int x2 = gq + 1; x2 <= N_GRAPHS; ++x2) start[x2] = N_NODES;
            }
        }
        if (t == WPB - 1) blockSums[blockIdx.x] = sS[WPB - 1];
    }
}

// ---- scan pass 2 -------------------------------------------------------------
__global__ __launch_bounds__(256) void k_scan2(unsigned* __restrict__ blockSums,
                                               unsigned* __restrict__ blockOff) {
    __shared__ unsigned s[256];
    int t = threadIdx.x;
    unsigned val = (t < NBR2) ? blockSums[t] : 0u;
    s[t] = val;
    __syncthreads();
    for (int off = 1; off < 256; off <<= 1) {
        unsigned x = (t >= off) ? s[t - off] : 0u;
        __syncthreads();
        s[t] += x;
        __syncthreads();
    }
    if (t < NBR2) blockOff[t] = s[t] - val;
}

// ---- fused: CSR place + fp16 prescale + W^T fp16 build ----------------------
__global__ __launch_bounds__(256) void k_prep(const int* __restrict__ src,
                                              const int* __restrict__ dst,
                                              const unsigned* __restrict__ Hin,
                                              const unsigned char* __restrict__ perm,
                                              const unsigned* __restrict__ row_ptr,
                                              const unsigned* __restrict__ blockOff,
                                              int* __restrict__ bsrc,
                                              const float* __restrict__ feat,
                                              const float* __restrict__ outnorm,
                                              _Float16* __restrict__ sfeat,
                                              const float* __restrict__ W,
                                              _Float16* __restrict__ Wt) {
    int t = threadIdx.x;
    int blk = blockIdx.x;
    if (blk < PLACE_BLKS) {
        int c = blk / PLACE_BPC;
        int i = (blk % PLACE_BPC) * 256 + t;
        if (i < CSZ) {
            int e = c * CSZ + i;
            int d = dst[e];
            int sh = (d & 3) * 8;
            unsigned pre = (Hin[(size_t)c * LQ + (d >> 2)] >> sh) & 0xffu;
            unsigned pos = row_ptr[d] + blockOff[d >> 8] + pre + perm[e];
            bsrc[pos] = src[e];
        }
    } else if (blk < PLACE_BLKS + PRES_BLKS) {
        int i = (blk - PLACE_BLKS) * 256 + t;
        if (i < N_NODES * DIM / 8) {
            int n = i >> 4;
            int d = (i & 15) << 3;
            float nrm = outnorm[n];
            const float4* p = reinterpret_cast<const float4*>(feat + (size_t)n * DIM + d);
            float4 a = p[0], q = p[1];
            h8 r;
            r[0] = (_Float16)(a.x * nrm); r[1] = (_Float16)(a.y * nrm);
            r[2] = (_Float16)(a.z * nrm); r[3] = (_Float16)(a.w * nrm);
            r[4] = (_Float16)(q.x * nrm); r[5] = (_Float16)(q.y * nrm);
            r[6] = (_Float16)(q.z * nrm); r[7] = (_Float16)(q.w * nrm);
            *reinterpret_cast<h8*>(sfeat + (size_t)n * DIM + d) = r;
        }
    } else {
        int i = (blk - PLACE_BLKS - PRES_BLKS) * 256 + t;  // i < DIM*DIM
        int n = i >> 7, k = i & 127;
        Wt[n * DIM + k] = (_Float16)W[k * DIM + n];
    }
}

#define CVT8(ACC_A, ACC_B, R, M) \
    ACC_A.x += (M) * (float)R[0]; ACC_A.y += (M) * (float)R[1]; \
    ACC_A.z += (M) * (float)R[2]; ACC_A.w += (M) * (float)R[3]; \
    ACC_B.x += (M) * (float)R[4]; ACC_B.y += (M) * (float)R[5]; \
    ACC_B.z += (M) * (float)R[6]; ACC_B.w += (M) * (float)R[7];

// ---- gather-sum over fp16 prescaled rows; OUTPUT IN FP16 --------------------
__global__ __launch_bounds__(256) void k_gather(const int* __restrict__ bsrc,
                                                const unsigned* __restrict__ row_ptr,
                                                const unsigned* __restrict__ blockOff,
                                                const unsigned* __restrict__ indeg,
                                                const _Float16* __restrict__ sfeat,
                                                const float* __restrict__ innorm,
                                                _Float16* __restrict__ aggh) {
    int tid = threadIdx.x;
    int wave = tid >> 6;
    int lane = tid & 63;
    int node = blockIdx.x * 4 + wave;
    if (node >= N_NODES) return;
    unsigned start = row_ptr[node] + blockOff[node >> 8];
    unsigned deg   = indeg[node];
    unsigned lim   = deg < 64u ? deg : 64u;
    int qtr = lane >> 4;
    int d8  = (lane & 15) << 3;
    int sIdx = 0;
    if ((unsigned)lane < lim) sIdx = bsrc[start + lane];
    float4 accA = {0,0,0,0}, accB = {0,0,0,0};
    for (unsigned j = 0; j < lim; j += 8) {
        unsigned j0 = j + qtr, j1 = j + 4 + qtr;
        int   s0 = __shfl(sIdx, (int)(j0 < lim ? j0 : 0u));
        int   s1 = __shfl(sIdx, (int)(j1 < lim ? j1 : 0u));
        float m0 = (j0 < lim) ? 1.f : 0.f;
        float m1 = (j1 < lim) ? 1.f : 0.f;
        h8 r0 = *reinterpret_cast<const h8*>(sfeat + (size_t)s0 * DIM + d8);
        h8 r1 = *reinterpret_cast<const h8*>(sfeat + (size_t)s1 * DIM + d8);
        CVT8(accA, accB, r0, m0);
        CVT8(accA, accB, r1, m1);
    }
    for (unsigned j = 64; j < deg; j += 4) {
        unsigned jj = j + qtr;
        bool valid = jj < deg;
        int s = bsrc[start + (valid ? jj : 0u)];
        float m = valid ? 1.f : 0.f;
        h8 r = *reinterpret_cast<const h8*>(sfeat + (size_t)s * DIM + d8);
        CVT8(accA, accB, r, m);
    }
    accA.x += __shfl_down(accA.x, 32); accA.y += __shfl_down(accA.y, 32);
    accA.z += __shfl_down(accA.z, 32); accA.w += __shfl_down(accA.w, 32);
    accB.x += __shfl_down(accB.x, 32); accB.y += __shfl_down(accB.y, 32);
    accB.z += __shfl_down(accB.z, 32); accB.w += __shfl_down(accB.w, 32);
    accA.x += __shfl_down(accA.x, 16); accA.y += __shfl_down(accA.y, 16);
    accA.z += __shfl_down(accA.z, 16); accA.w += __shfl_down(accA.w, 16);
    accB.x += __shfl_down(accB.x, 16); accB.y += __shfl_down(accB.y, 16);
    accB.z += __shfl_down(accB.z, 16); accB.w += __shfl_down(accB.w, 16);
    if (qtr == 0) {
        float innrm = innorm[node];
        h8 r;
        r[0] = (_Float16)(accA.x * innrm); r[1] = (_Float16)(accA.y * innrm);
        r[2] = (_Float16)(accA.z * innrm); r[3] = (_Float16)(accA.w * innrm);
        r[4] = (_Float16)(accB.x * innrm); r[5] = (_Float16)(accB.y * innrm);
        r[6] = (_Float16)(accB.z * innrm); r[7] = (_Float16)(accB.w * innrm);
        *reinterpret_cast<h8*>(aggh + (size_t)node * DIM + d8) = r;
    }
}

// ---- node transform via MFMA + fused mean-pool ------------------------------
// Wave: 32 nodes x 128 outs, mfma_f32_16x16x32_f16 (4 K-steps x 8 col-tiles
// x 2 node-groups). A from aggh (fp16, 16B/lane), B from Wt (fp16 W^T,
// L1-resident). C layout: col=lane&15, row=quad*4+reg. Epilogue: bias+relu,
// per-graph register pool accumulators (<=2 graphs/block typical; atomic
// fallback otherwise), quad-shfl + LDS cross-wave reduce, ~128 atomics/block.
__global__ __launch_bounds__(256) void k_node(const _Float16* __restrict__ aggh,
                                              const int* __restrict__ gid,
                                              const _Float16* __restrict__ Wt,
                                              const float* __restrict__ b,
                                              float* __restrict__ pooled) {
    __shared__ float red[4][2][DIM];   // 4 KB
    int tid = threadIdx.x;
    int wave = tid >> 6, lane = tid & 63;
    int quad = lane >> 4, m = lane & 15;
    int blockBase = blockIdx.x * NPBM;
    int wbase = blockBase + wave * 32;
    int gfirst = gid[blockBase];
    int gsec = gfirst + 1;

    f4v acc0[8], acc1[8];
#pragma unroll
    for (int t = 0; t < 8; ++t) { acc0[t] = (f4v){0,0,0,0}; acc1[t] = (f4v){0,0,0,0}; }

#pragma unroll
    for (int kk = 0; kk < 4; ++kk) {
        int ko = kk * 32 + quad * 8;
        h8 a0 = *reinterpret_cast<const h8*>(aggh + (size_t)(wbase + m) * DIM + ko);
        h8 a1 = *reinterpret_cast<const h8*>(aggh + (size_t)(wbase + 16 + m) * DIM + ko);
#pragma unroll
        for (int t = 0; t < 8; ++t) {
            h8 bf = *reinterpret_cast<const h8*>(Wt + (size_t)(t * 16 + m) * DIM + ko);
            acc0[t] = __builtin_amdgcn_mfma_f32_16x16x32_f16(a0, bf, acc0[t], 0, 0, 0);
            acc1[t] = __builtin_amdgcn_mfma_f32_16x16x32_f16(a1, bf, acc1[t], 0, 0, 0);
        }
    }

    // epilogue: bias + relu + pool
    int n0 = wbase + quad * 4;        // group-0 node base for regs 0..3
    int n1 = n0 + 16;                 // group-1
    float s0[8], s1[8];
#pragma unroll
    for (int t = 0; t < 8; ++t) {
        float bb = b[t * 16 + m];
        s0[t] = 0.f; s1[t] = 0.f;
#pragma unroll
        for (int r = 0; r < 4; ++r) {
            int node = n0 + r;
            if (node < N_NODES) {
                float h = fmaxf(acc0[t][r] + bb, 0.f);
                int g = gid[node];
                if (g == gfirst)      s0[t] += h;
                else if (g == gsec)   s1[t] += h;
                else atomicAdd(&pooled[(size_t)g * DIM + t * 16 + m], h);
            }
            int node2 = n1 + r;
            if (node2 < N_NODES) {
                float h = fmaxf(acc1[t][r] + bb, 0.f);
                int g = gid[node2];
                if (g == gfirst)      s0[t] += h;
                else if (g == gsec)   s1[t] += h;
                else atomicAdd(&pooled[(size_t)g * DIM + t * 16 + m], h);
            }
        }
        s0[t] += __shfl_down(s0[t], 32);
        s0[t] += __shfl_down(s0[t], 16);
        s1[t] += __shfl_down(s1[t], 32);
        s1[t] += __shfl_down(s1[t], 16);
    }
    if (quad == 0) {
#pragma unroll
        for (int t = 0; t < 8; ++t) {
            red[wave][0][t * 16 + m] = s0[t];
            red[wave][1][t * 16 + m] = s1[t];
        }
    }
    __syncthreads();
    if (tid < DIM) {
        float v0 = red[0][0][tid] + red[1][0][tid] + red[2][0][tid] + red[3][0][tid];
        if (v0 != 0.f) atomicAdd(&pooled[(size_t)gfirst * DIM + tid], v0);
        float v1 = red[0][1][tid] + red[1][1][tid] + red[2][1][tid] + red[3][1][tid];
        if (v1 != 0.f && gsec < N_GRAPHS) atomicAdd(&pooled[(size_t)gsec * DIM + tid], v1);
    }
}

// ---- head: out = (pooled/cnt) @ W_head + b_head -----------------------------
__global__ __launch_bounds__(256) void k_head(const float* __restrict__ pooled,
                                              const int* __restrict__ start,
                                              const float* __restrict__ Wh,
                                              const float* __restrict__ bh,
                                              float* __restrict__ out) {
    int i = blockIdx.x * 256 + threadIdx.x;
    if (i >= N_GRAPHS * N_CLASSES) return;
    int g = i / N_CLASSES, c = i % N_CLASSES;
    const float* pr = pooled + g * DIM;
    float s = 0.f;
#pragma unroll 8
    for (int k = 0; k < DIM; ++k) s += pr[k] * Wh[k * N_CLASSES + c];
    float cntf = fmaxf((float)(start[g + 1] - start[g]), 1.0f);
    out[i] = s / cntf + bh[c];
}

extern "C" void kernel_launch(void* const* d_in, const int* in_sizes, int n_in,
                              void* d_out, int out_size, void* d_ws, size_t ws_size,
                              hipStream_t stream) {
    const float* feat = (const float*)d_in[0];
    const int*   src  = (const int*)d_in[1];
    const int*   dst  = (const int*)d_in[2];
    const int*   gid  = (const int*)d_in[3];
    const float* W    = (const float*)d_in[4];
    const float* b    = (const float*)d_in[5];
    const float* Wh   = (const float*)d_in[6];
    const float* bh   = (const float*)d_in[7];
    float* out = (float*)d_out;

    // ---- workspace layout (4-byte elements) ----
    float*    pooled   = (float*)d_ws;                                  // G*D (zeroed)
    unsigned* indeg    = (unsigned*)(pooled + (size_t)N_GRAPHS * DIM);  // N
    float*    outnorm  = (float*)(indeg + N_NODES);                     // N
    float*    innorm   = outnorm + N_NODES;                             // N
    int*      start    = (int*)(innorm + N_NODES);                      // G+1
    unsigned* row_ptr  = (unsigned*)(start + N_GRAPHS + 1);             // N
    unsigned* blockSums= row_ptr + N_NODES;                             // 256
    unsigned* blockOff = blockSums + 256;                               // 256
    unsigned char* perm= (unsigned char*)(blockOff + 256);              // E bytes
    int*      bsrc     = (int*)(perm + N_EDGES);                        // E
    _Float16* sfeat    = (_Float16*)(bsrc + N_EDGES);                   // N*D halves
    _Float16* aggh     = sfeat + (size_t)N_NODES * DIM;                 // N*D halves
    _Float16* Wt       = aggh + (size_t)N_NODES * DIM;                  // DIM*DIM halves
    unsigned* Hin      = (unsigned*)(Wt + DIM * DIM);                   // NCHE*LQ
    unsigned* Hout     = Hin + (size_t)NCHE * LQ;                       // NCHE*LQ
    // note: aggh OOB reads (last k_node block, masked rows) land in Wt/Hin — benign

    hipMemsetAsync(pooled, 0, (size_t)N_GRAPHS * DIM * 4, stream);

    dim3 lh(NCHE, 2);
    k_lhist <<<lh, 256, 0, stream>>>(src, dst, Hin, Hout, perm);
    k_reduce<<<NBR2, 256, 0, stream>>>(Hin, Hout, gid, indeg, outnorm, innorm,
                                       start, row_ptr, blockSums);
    k_scan2 <<<1, 256, 0, stream>>>(blockSums, blockOff);
    k_prep  <<<PLACE_BLKS + PRES_BLKS + WT_BLKS, 256, 0, stream>>>(
                src, dst, Hin, perm, row_ptr, blockOff, bsrc,
                feat, outnorm, sfeat, W, Wt);
    k_gather<<<(N_NODES + 3) / 4, 256, 0, stream>>>(bsrc, row_ptr, blockOff, indeg,
                                                    sfeat, innorm, aggh);
    k_node  <<<NBLK_NODE, 256, 0, stream>>>(aggh, gid, Wt, b, pooled);
    k_head  <<<3, 256, 0, stream>>>(pooled, start, Wh, bh, out);
}

// Round 12
// 188.256 us; speedup vs baseline: 1.5901x; 1.0987x over previous
//
#include <hip/hip_runtime.h>

#define N_NODES   50000
#define N_EDGES   800000
#define DIM       128
#define N_GRAPHS  64
#define N_CLASSES 10
#define NCHE      128                  // edge chunks (u8-safe: max count <= deg ~45)
#define CSZ       (N_EDGES / NCHE)     // 6250
#define LQ        (N_NODES / 4)        // 12500 u8-packed words (4 nodes/word)
#define WPB       64                   // words per reduce block (256 nodes)
#define NBR2      ((LQ + WPB - 1) / WPB)   // 196
#define PLACE_BPC ((CSZ + 255) / 256)      // 25
#define PLACE_BLKS (NCHE * PLACE_BPC)      // 3200
#define PRES_BLKS ((N_NODES * DIM / 8 + 255) / 256)  // 3125
#define WT_BLKS   (DIM * DIM / 256)        // 64
#define NPBM      128                  // nodes per block in k_node (MFMA)
#define NBLK_NODE ((N_NODES + NPBM - 1) / NPBM)  // 391

typedef _Float16 h8 __attribute__((ext_vector_type(8)));
typedef float f4v __attribute__((ext_vector_type(4)));

// ---- per-chunk LDS histograms (u8 packed), dst/src phases in parallel blocks
__global__ __launch_bounds__(256) void k_lhist(const int* __restrict__ src,
                                               const int* __restrict__ dst,
                                               unsigned* __restrict__ Hin,
                                               unsigned* __restrict__ Hout,
                                               unsigned char* __restrict__ perm) {
    __shared__ unsigned L[LQ];         // 50 KB
    int c = blockIdx.x, t = threadIdx.x;
    int base = c * CSZ;
    for (int w = t; w < LQ; w += 256) L[w] = 0u;
    __syncthreads();
    if (blockIdx.y == 0) {
        for (int i = t; i < CSZ; i += 256) {
            int d = dst[base + i];
            int sh = (d & 3) * 8;
            unsigned old = atomicAdd(&L[d >> 2], 1u << sh);
            perm[base + i] = (unsigned char)((old >> sh) & 0xffu);
        }
        __syncthreads();
        for (int w = t; w < LQ; w += 256) Hin[(size_t)c * LQ + w] = L[w];
    } else {
        for (int i = t; i < CSZ; i += 256) {
            int s = src[base + i];
            atomicAdd(&L[s >> 2], 1u << ((s & 3) * 8));
        }
        __syncthreads();
        for (int w = t; w < LQ; w += 256) Hout[(size_t)c * LQ + w] = L[w];
    }
}

// ---- reduce: degrees/norms; Hin := per-chunk prefix; boundaries; scan p1 ----
__global__ __launch_bounds__(256) void k_reduce(unsigned* __restrict__ Hin,
                                                const unsigned* __restrict__ Hout,
                                                const int* __restrict__ gid,
                                                unsigned* __restrict__ indeg,
                                                float* __restrict__ outnorm,
                                                float* __restrict__ innorm,
                                                int* __restrict__ start,
                                                unsigned* __restrict__ row_ptr,
                                                unsigned* __restrict__ blockSums) {
    __shared__ unsigned sIn[4][WPB];
    __shared__ unsigned sOut[4][WPB];
    __shared__ unsigned sS[WPB];
    int t = threadIdx.x;
    int wl = t & (WPB - 1);
    int g  = t >> 6;
    int w  = blockIdx.x * WPB + wl;
    unsigned gs = 0, os = 0;
    int c0 = g * (NCHE / 4);
    if (w < LQ) {
        for (int c = c0; c < c0 + NCHE / 4; ++c) {
            gs += Hin[(size_t)c * LQ + w];
            os += Hout[(size_t)c * LQ + w];
        }
    }
    sIn[g][wl] = gs; sOut[g][wl] = os;
    __syncthreads();
    unsigned baseg = 0;
    for (int gg = 0; gg < 4; ++gg) if (gg < g) baseg += sIn[gg][wl];
    if (w < LQ) {
        unsigned running = baseg;
        for (int c = c0; c < c0 + NCHE / 4; ++c) {
            size_t idx = (size_t)c * LQ + w;
            unsigned word = Hin[idx];
            Hin[idx] = running;
            running += word;
        }
    }
    unsigned tot = 0, otot = 0, wtot = 0;
    if (t < WPB) {
        tot  = sIn[0][t] + sIn[1][t] + sIn[2][t] + sIn[3][t];
        otot = sOut[0][t] + sOut[1][t] + sOut[2][t] + sOut[3][t];
        wtot = (tot & 0xffu) + ((tot >> 8) & 0xffu) + ((tot >> 16) & 0xffu) + (tot >> 24);
        sS[t] = wtot;
    }
    __syncthreads();
    for (int off = 1; off < WPB; off <<= 1) {
        unsigned x = (t < WPB && t >= off) ? sS[t - off] : 0u;
        __syncthreads();
        if (t < WPB) sS[t] += x;
        __syncthreads();
    }
    if (t < WPB) {
        int ww = blockIdx.x * WPB + t;
        if (ww < LQ) {
            unsigned r0 = tot & 0xffu, r1 = (tot >> 8) & 0xffu,
                     r2 = (tot >> 16) & 0xffu, r3 = tot >> 24;
            unsigned o0 = otot & 0xffu, o1 = (otot >> 8) & 0xffu,
                     o2 = (otot >> 16) & 0xffu, o3 = otot >> 24;
            unsigned ex = sS[t] - wtot;
            int n = 4 * ww;
            row_ptr[n]     = ex;
            row_ptr[n + 1] = ex + r0;
            row_ptr[n + 2] = ex + r0 + r1;
            row_ptr[n + 3] = ex + r0 + r1 + r2;
            unsigned rr[4] = {r0, r1, r2, r3}, oo[4] = {o0, o1, o2, o3};
#pragma unroll
            for (int j = 0; j < 4; ++j) {
                indeg[n + j]   = rr[j];
                innorm[n + j]  = rsqrtf(fmaxf((float)rr[j], 1.0f));
                outnorm[n + j] = rsqrtf(fmaxf((float)oo[j], 1.0f));
                int i = n + j;
                int gq = gid[i];
                if (i == 0) {
                    for (int x2 = 0; x2 <= gq; ++x2) start[x2] = 0;
                } else {
                    int gp = gid[i - 1];
                    if (gp != gq)
                        for (int x2 = gp + 1; x2 <= gq; ++x2) start[x2] = i;
                }
                if (i == N_NODES - 1)
                    for (int x2 = gq + 1; x2 <= N_GRAPHS; ++x2) start[x2] = N_NODES;
            }
        }
        if (t == WPB - 1) blockSums[blockIdx.x] = sS[WPB - 1];
    }
}

// ---- scan pass 2 + pooled zeroing (replaces the memset dispatch) ------------
__global__ __launch_bounds__(256) void k_scan2(unsigned* __restrict__ blockSums,
                                               unsigned* __restrict__ blockOff,
                                               float* __restrict__ pooled) {
    __shared__ unsigned s[256];
    int t = threadIdx.x;
    unsigned val = (t < NBR2) ? blockSums[t] : 0u;
    s[t] = val;
    __syncthreads();
    for (int off = 1; off < 256; off <<= 1) {
        unsigned x = (t >= off) ? s[t - off] : 0u;
        __syncthreads();
        s[t] += x;
        __syncthreads();
    }
    if (t < NBR2) blockOff[t] = s[t] - val;
    float4 z = {0.f, 0.f, 0.f, 0.f};
    for (int i = t; i < N_GRAPHS * DIM / 4; i += 256)
        reinterpret_cast<float4*>(pooled)[i] = z;
}

// ---- fused: CSR place + fp16 prescale + W^T fp16 build ----------------------
__global__ __launch_bounds__(256) void k_prep(const int* __restrict__ src,
                                              const int* __restrict__ dst,
                                              const unsigned* __restrict__ Hin,
                                              const unsigned char* __restrict__ perm,
                                              const unsigned* __restrict__ row_ptr,
                                              const unsigned* __restrict__ blockOff,
                                              int* __restrict__ bsrc,
                                              const float* __restrict__ feat,
                                              const float* __restrict__ outnorm,
                                              _Float16* __restrict__ sfeat,
                                              const float* __restrict__ W,
                                              _Float16* __restrict__ Wt) {
    int t = threadIdx.x;
    int blk = blockIdx.x;
    if (blk < PLACE_BLKS) {
        int c = blk / PLACE_BPC;
        int i = (blk % PLACE_BPC) * 256 + t;
        if (i < CSZ) {
            int e = c * CSZ + i;
            int d = dst[e];
            int sh = (d & 3) * 8;
            unsigned pre = (Hin[(size_t)c * LQ + (d >> 2)] >> sh) & 0xffu;
            unsigned pos = row_ptr[d] + blockOff[d >> 8] + pre + perm[e];
            bsrc[pos] = src[e];
        }
    } else if (blk < PLACE_BLKS + PRES_BLKS) {
        int i = (blk - PLACE_BLKS) * 256 + t;
        if (i < N_NODES * DIM / 8) {
            int n = i >> 4;
            int d = (i & 15) << 3;
            float nrm = outnorm[n];
            const float4* p = reinterpret_cast<const float4*>(feat + (size_t)n * DIM + d);
            float4 a = p[0], q = p[1];
            h8 r;
            r[0] = (_Float16)(a.x * nrm); r[1] = (_Float16)(a.y * nrm);
            r[2] = (_Float16)(a.z * nrm); r[3] = (_Float16)(a.w * nrm);
            r[4] = (_Float16)(q.x * nrm); r[5] = (_Float16)(q.y * nrm);
            r[6] = (_Float16)(q.z * nrm); r[7] = (_Float16)(q.w * nrm);
            *reinterpret_cast<h8*>(sfeat + (size_t)n * DIM + d) = r;
        }
    } else {
        int i = (blk - PLACE_BLKS - PRES_BLKS) * 256 + t;  // i < DIM*DIM
        int n = i >> 7, k = i & 127;
        Wt[n * DIM + k] = (_Float16)W[k * DIM + n];
    }
}

#define CVT8(ACC_A, ACC_B, R, M) \
    ACC_A.x += (M) * (float)R[0]; ACC_A.y += (M) * (float)R[1]; \
    ACC_A.z += (M) * (float)R[2]; ACC_A.w += (M) * (float)R[3]; \
    ACC_B.x += (M) * (float)R[4]; ACC_B.y += (M) * (float)R[5]; \
    ACC_B.z += (M) * (float)R[6]; ACC_B.w += (M) * (float)R[7];

// ---- gather-sum over fp16 prescaled rows; 4 rows in flight per iteration ----
__global__ __launch_bounds__(256) void k_gather(const int* __restrict__ bsrc,
                                                const unsigned* __restrict__ row_ptr,
                                                const unsigned* __restrict__ blockOff,
                                                const unsigned* __restrict__ indeg,
                                                const _Float16* __restrict__ sfeat,
                                                const float* __restrict__ innorm,
                                                _Float16* __restrict__ aggh) {
    int tid = threadIdx.x;
    int wave = tid >> 6;
    int lane = tid & 63;
    int node = blockIdx.x * 4 + wave;
    if (node >= N_NODES) return;
    unsigned start = row_ptr[node] + blockOff[node >> 8];
    unsigned deg   = indeg[node];
    unsigned lim   = deg < 64u ? deg : 64u;
    int qtr = lane >> 4;
    int d8  = (lane & 15) << 3;
    int sIdx = 0;
    if ((unsigned)lane < lim) sIdx = bsrc[start + lane];
    float4 accA = {0,0,0,0}, accB = {0,0,0,0};
    float4 accC = {0,0,0,0}, accD = {0,0,0,0};
    for (unsigned j = 0; j < lim; j += 16) {
        unsigned j0 = j + qtr, j1 = j + 4 + qtr, j2 = j + 8 + qtr, j3 = j + 12 + qtr;
        int s0 = __shfl(sIdx, (int)(j0 < lim ? j0 : 0u));
        int s1 = __shfl(sIdx, (int)(j1 < lim ? j1 : 0u));
        int s2 = __shfl(sIdx, (int)(j2 < lim ? j2 : 0u));
        int s3 = __shfl(sIdx, (int)(j3 < lim ? j3 : 0u));
        float m0 = (j0 < lim) ? 1.f : 0.f;
        float m1 = (j1 < lim) ? 1.f : 0.f;
        float m2 = (j2 < lim) ? 1.f : 0.f;
        float m3 = (j3 < lim) ? 1.f : 0.f;
        h8 r0 = *reinterpret_cast<const h8*>(sfeat + (size_t)s0 * DIM + d8);
        h8 r1 = *reinterpret_cast<const h8*>(sfeat + (size_t)s1 * DIM + d8);
        h8 r2 = *reinterpret_cast<const h8*>(sfeat + (size_t)s2 * DIM + d8);
        h8 r3 = *reinterpret_cast<const h8*>(sfeat + (size_t)s3 * DIM + d8);
        CVT8(accA, accB, r0, m0);
        CVT8(accC, accD, r1, m1);
        CVT8(accA, accB, r2, m2);
        CVT8(accC, accD, r3, m3);
    }
    for (unsigned j = 64; j < deg; j += 4) {   // overflow: deg > 64
        unsigned jj = j + qtr;
        bool valid = jj < deg;
        int s = bsrc[start + (valid ? jj : 0u)];
        float m = valid ? 1.f : 0.f;
        h8 r = *reinterpret_cast<const h8*>(sfeat + (size_t)s * DIM + d8);
        CVT8(accA, accB, r, m);
    }
    accA.x += accC.x; accA.y += accC.y; accA.z += accC.z; accA.w += accC.w;
    accB.x += accD.x; accB.y += accD.y; accB.z += accD.z; accB.w += accD.w;
    accA.x += __shfl_down(accA.x, 32); accA.y += __shfl_down(accA.y, 32);
    accA.z += __shfl_down(accA.z, 32); accA.w += __shfl_down(accA.w, 32);
    accB.x += __shfl_down(accB.x, 32); accB.y += __shfl_down(accB.y, 32);
    accB.z += __shfl_down(accB.z, 32); accB.w += __shfl_down(accB.w, 32);
    accA.x += __shfl_down(accA.x, 16); accA.y += __shfl_down(accA.y, 16);
    accA.z += __shfl_down(accA.z, 16); accA.w += __shfl_down(accA.w, 16);
    accB.x += __shfl_down(accB.x, 16); accB.y += __shfl_down(accB.y, 16);
    accB.z += __shfl_down(accB.z, 16); accB.w += __shfl_down(accB.w, 16);
    if (qtr == 0) {
        float innrm = innorm[node];
        h8 r;
        r[0] = (_Float16)(accA.x * innrm); r[1] = (_Float16)(accA.y * innrm);
        r[2] = (_Float16)(accA.z * innrm); r[3] = (_Float16)(accA.w * innrm);
        r[4] = (_Float16)(accB.x * innrm); r[5] = (_Float16)(accB.y * innrm);
        r[6] = (_Float16)(accB.z * innrm); r[7] = (_Float16)(accB.w * innrm);
        *reinterpret_cast<h8*>(aggh + (size_t)node * DIM + d8) = r;
    }
}

// ---- node transform via MFMA + fused mean-pool ------------------------------
__global__ __launch_bounds__(256) void k_node(const _Float16* __restrict__ aggh,
                                              const int* __restrict__ gid,
                                              const _Float16* __restrict__ Wt,
                                              const float* __restrict__ b,
                                              float* __restrict__ pooled) {
    __shared__ float red[4][2][DIM];   // 4 KB
    int tid = threadIdx.x;
    int wave = tid >> 6, lane = tid & 63;
    int quad = lane >> 4, m = lane & 15;
    int blockBase = blockIdx.x * NPBM;
    int wbase = blockBase + wave * 32;
    int gfirst = gid[blockBase];
    int gsec = gfirst + 1;

    f4v acc0[8], acc1[8];
#pragma unroll
    for (int t = 0; t < 8; ++t) { acc0[t] = (f4v){0,0,0,0}; acc1[t] = (f4v){0,0,0,0}; }

#pragma unroll
    for (int kk = 0; kk < 4; ++kk) {
        int ko = kk * 32 + quad * 8;
        h8 a0 = *reinterpret_cast<const h8*>(aggh + (size_t)(wbase + m) * DIM + ko);
        h8 a1 = *reinterpret_cast<const h8*>(aggh + (size_t)(wbase + 16 + m) * DIM + ko);
#pragma unroll
        for (int t = 0; t < 8; ++t) {
            h8 bf = *reinterpret_cast<const h8*>(Wt + (size_t)(t * 16 + m) * DIM + ko);
            acc0[t] = __builtin_amdgcn_mfma_f32_16x16x32_f16(a0, bf, acc0[t], 0, 0, 0);
            acc1[t] = __builtin_amdgcn_mfma_f32_16x16x32_f16(a1, bf, acc1[t], 0, 0, 0);
        }
    }

    int n0 = wbase + quad * 4;
    int n1 = n0 + 16;
    float s0[8], s1[8];
#pragma unroll
    for (int t = 0; t < 8; ++t) {
        float bb = b[t * 16 + m];
        s0[t] = 0.f; s1[t] = 0.f;
#pragma unroll
        for (int r = 0; r < 4; ++r) {
            int node = n0 + r;
            if (node < N_NODES) {
                float h = fmaxf(acc0[t][r] + bb, 0.f);
                int g = gid[node];
                if (g == gfirst)      s0[t] += h;
                else if (g == gsec)   s1[t] += h;
                else atomicAdd(&pooled[(size_t)g * DIM + t * 16 + m], h);
            }
            int node2 = n1 + r;
            if (node2 < N_NODES) {
                float h = fmaxf(acc1[t][r] + bb, 0.f);
                int g = gid[node2];
                if (g == gfirst)      s0[t] += h;
                else if (g == gsec)   s1[t] += h;
                else atomicAdd(&pooled[(size_t)g * DIM + t * 16 + m], h);
            }
        }
        s0[t] += __shfl_down(s0[t], 32);
        s0[t] += __shfl_down(s0[t], 16);
        s1[t] += __shfl_down(s1[t], 32);
        s1[t] += __shfl_down(s1[t], 16);
    }
    if (quad == 0) {
#pragma unroll
        for (int t = 0; t < 8; ++t) {
            red[wave][0][t * 16 + m] = s0[t];
            red[wave][1][t * 16 + m] = s1[t];
        }
    }
    __syncthreads();
    if (tid < DIM) {
        float v0 = red[0][0][tid] + red[1][0][tid] + red[2][0][tid] + red[3][0][tid];
        if (v0 != 0.f) atomicAdd(&pooled[(size_t)gfirst * DIM + tid], v0);
        float v1 = red[0][1][tid] + red[1][1][tid] + red[2][1][tid] + red[3][1][tid];
        if (v1 != 0.f && gsec < N_GRAPHS) atomicAdd(&pooled[(size_t)gsec * DIM + tid], v1);
    }
}

// ---- head: out = (pooled/cnt) @ W_head + b_head -----------------------------
__global__ __launch_bounds__(256) void k_head(const float* __restrict__ pooled,
                                              const int* __restrict__ start,
                                              const float* __restrict__ Wh,
                                              const float* __restrict__ bh,
                                              float* __restrict__ out) {
    int i = blockIdx.x * 256 + threadIdx.x;
    if (i >= N_GRAPHS * N_CLASSES) return;
    int g = i / N_CLASSES, c = i % N_CLASSES;
    const float* pr = pooled + g * DIM;
    float s = 0.f;
#pragma unroll 8
    for (int k = 0; k < DIM; ++k) s += pr[k] * Wh[k * N_CLASSES + c];
    float cntf = fmaxf((float)(start[g + 1] - start[g]), 1.0f);
    out[i] = s / cntf + bh[c];
}

extern "C" void kernel_launch(void* const* d_in, const int* in_sizes, int n_in,
                              void* d_out, int out_size, void* d_ws, size_t ws_size,
                              hipStream_t stream) {
    const float* feat = (const float*)d_in[0];
    const int*   src  = (const int*)d_in[1];
    const int*   dst  = (const int*)d_in[2];
    const int*   gid  = (const int*)d_in[3];
    const float* W    = (const float*)d_in[4];
    const float* b    = (const float*)d_in[5];
    const float* Wh   = (const float*)d_in[6];
    const float* bh   = (const float*)d_in[7];
    float* out = (float*)d_out;

    // ---- workspace layout (4-byte elements) ----
    float*    pooled   = (float*)d_ws;                                  // G*D
    unsigned* indeg    = (unsigned*)(pooled + (size_t)N_GRAPHS * DIM);  // N
    float*    outnorm  = (float*)(indeg + N_NODES);                     // N
    float*    innorm   = outnorm + N_NODES;                             // N
    int*      start    = (int*)(innorm + N_NODES);                      // G+1
    unsigned* row_ptr  = (unsigned*)(start + N_GRAPHS + 1);             // N
    unsigned* blockSums= row_ptr + N_NODES;                             // 256
    unsigned* blockOff = blockSums + 256;                               // 256
    unsigned char* perm= (unsigned char*)(blockOff + 256);              // E bytes
    int*      bsrc     = (int*)(perm + N_EDGES);                        // E
    _Float16* sfeat    = (_Float16*)(bsrc + N_EDGES);                   // N*D halves
    _Float16* aggh     = sfeat + (size_t)N_NODES * DIM;                 // N*D halves
    _Float16* Wt       = aggh + (size_t)N_NODES * DIM;                  // DIM*DIM halves
    unsigned* Hin      = (unsigned*)(Wt + DIM * DIM);                   // NCHE*LQ
    unsigned* Hout     = Hin + (size_t)NCHE * LQ;                       // NCHE*LQ

    dim3 lh(NCHE, 2);
    k_lhist <<<lh, 256, 0, stream>>>(src, dst, Hin, Hout, perm);
    k_reduce<<<NBR2, 256, 0, stream>>>(Hin, Hout, gid, indeg, outnorm, innorm,
                                       start, row_ptr, blockSums);
    k_scan2 <<<1, 256, 0, stream>>>(blockSums, blockOff, pooled);
    k_prep  <<<PLACE_BLKS + PRES_BLKS + WT_BLKS, 256, 0, stream>>>(
                src, dst, Hin, perm, row_ptr, blockOff, bsrc,
                feat, outnorm, sfeat, W, Wt);
    k_gather<<<(N_NODES + 3) / 4, 256, 0, stream>>>(bsrc, row_ptr, blockOff, indeg,
                                                    sfeat, innorm, aggh);
    k_node  <<<NBLK_NODE, 256, 0, stream>>>(aggh, gid, Wt, b, pooled);
    k_head  <<<3, 256, 0, stream>>>(pooled, start, Wh, bh, out);
}